// Round 9
// baseline (748.006 us; speedup 1.0000x reference)
//
#include <hip/hip_runtime.h>
#include <math.h>

#define BATCH 8
#define NPTS 2048
#define KF 1024

typedef _Float16 f16x8 __attribute__((ext_vector_type(8)));
typedef float f32x4 __attribute__((ext_vector_type(4)));

// 16x16x32 layouts HW-verified (m89/m91/m97/m120):
//  A: lane holds A[m=lane&15][k=(lane>>4)*8+j]
//  B: lane holds B[k=(lane>>4)*8+j][n=lane&15]
//  C/D: lane,reg holds C[row=(lane>>4)*4+reg][col=lane&15]
#define MFMA16(a,b,c) __builtin_amdgcn_mfma_f32_16x16x32_f16((a),(b),(c),0,0,0)

#define FSCALE 256.0f
#define INV16  (1.0f/65536.0f)

// fp16 2-way split of (x*256); 3 products (hh, hl, lh), ll dropped (~4e-4 on r).
__device__ __forceinline__ void split_f16s(float x, _Float16& hi, _Float16& lo) {
  float xs = x * FSCALE;
  hi = (_Float16)xs;
  lo = (_Float16)(xs - (float)hi);
}

// ---------------- misc device helpers ----------------
__device__ __forceinline__ void mat3mul(const float* A, const float* Bm, float* C) {
#pragma unroll
  for (int i = 0; i < 3; ++i)
#pragma unroll
    for (int j = 0; j < 3; ++j)
      C[i*3+j] = A[i*3+0]*Bm[0*3+j] + A[i*3+1]*Bm[1*3+j] + A[i*3+2]*Bm[2*3+j];
}

__device__ void se3_exp_dev(const float* x, float* R, float* p) {
  float wx = x[0], wy = x[1], wz = x[2];
  float vx = x[3], vy = x[4], vz = x[5];
  float t2 = wx*wx + wy*wy + wz*wz;
  float t = sqrtf(t2);
  float A, Bc, Cc;
  if (t < 1e-6f) {
    A  = 1.f - t2*(1.f/6.f);
    Bc = 0.5f - t2*(1.f/24.f);
    Cc = (1.f/6.f) - t2*(1.f/120.f);
  } else {
    float s = sinf(t), c = cosf(t);
    A  = s / t;
    Bc = (1.f - c) / t2;
    Cc = (t - s) / (t2 * t);
  }
  float W[9]  = {0.f, -wz, wy,  wz, 0.f, -wx,  -wy, wx, 0.f};
  float W2[9];
  mat3mul(W, W, W2);
#pragma unroll
  for (int i = 0; i < 9; ++i) {
    float I = (i == 0 || i == 4 || i == 8) ? 1.f : 0.f;
    R[i] = I + A*W[i] + Bc*W2[i];
  }
  float V[9];
#pragma unroll
  for (int i = 0; i < 9; ++i) {
    float I = (i == 0 || i == 4 || i == 8) ? 1.f : 0.f;
    V[i] = I + Bc*W[i] + Cc*W2[i];
  }
  p[0] = V[0]*vx + V[1]*vy + V[2]*vz;
  p[1] = V[3]*vx + V[4]*vy + V[5]*vz;
  p[2] = V[6]*vx + V[7]*vy + V[8]*vz;
}

// ---------------- small kernels (verified) ----------------
__global__ void means_kernel(const float* __restrict__ tgt, const float* __restrict__ src,
                             float* __restrict__ mean_tgt, float* __restrict__ mean_src) {
  int which = blockIdx.x & 1, b = blockIdx.x >> 1;
  const float* p = (which ? src : tgt) + (size_t)b*NPTS*3;
  float* m = (which ? mean_src : mean_tgt) + b*3;
  int t = threadIdx.x;
  float s0 = 0.f, s1 = 0.f, s2 = 0.f;
  for (int i = t; i < NPTS; i += 256) {
    s0 += p[i*3+0]; s1 += p[i*3+1]; s2 += p[i*3+2];
  }
  __shared__ float red[256][3];
  red[t][0] = s0; red[t][1] = s1; red[t][2] = s2;
  __syncthreads();
  for (int s = 128; s > 0; s >>= 1) {
    if (t < s) { red[t][0] += red[t+s][0]; red[t][1] += red[t+s][1]; red[t][2] += red[t+s][2]; }
    __syncthreads();
  }
  if (t == 0) {
    m[0] = red[0][0] * (1.f/NPTS);
    m[1] = red[0][1] * (1.f/NPTS);
    m[2] = red[0][2] * (1.f/NPTS);
  }
}

__global__ void setup_kernel(const float* __restrict__ dt, const float* __restrict__ W1,
                             const float* __restrict__ b1, const float* __restrict__ igt_twist,
                             float* __restrict__ W1eff7, float* __restrict__ b1eff7,
                             float* __restrict__ W1effL, float* __restrict__ b1effL,
                             float* __restrict__ g_buf, float* __restrict__ igt_inv,
                             float* __restrict__ loss_out) {
  int t = threadIdx.x;
  for (int i = t; i < BATCH*192;  i += 256) W1effL[i] = W1[i % 192];
  for (int i = t; i < BATCH*64;   i += 256) b1effL[i] = b1[i & 63];
  if (t < 192) W1eff7[t] = W1[t];
  if (t < 64)  b1eff7[t] = b1[t];
  if (t < BATCH*16) {
    int i = t & 15;
    g_buf[t] = (i == 0 || i == 5 || i == 10 || i == 15) ? 1.f : 0.f;
  }
  if (t == 0) *loss_out = 0.f;
  if (t < 6) {
    float tw[6] = {0.f,0.f,0.f,0.f,0.f,0.f};
    tw[t] = -dt[t];
    float R[9], tr[3];
    se3_exp_dev(tw, R, tr);
    float* Wd = W1eff7 + (t+1)*192;
    for (int d = 0; d < 3; ++d)
      for (int c = 0; c < 64; ++c)
        Wd[d*64+c] = R[0*3+d]*W1[c] + R[1*3+d]*W1[64+c] + R[2*3+d]*W1[128+c];
    float* bd = b1eff7 + (t+1)*64;
    for (int c = 0; c < 64; ++c)
      bd[c] = b1[c] + tr[0]*W1[c] + tr[1]*W1[64+c] + tr[2]*W1[128+c];
  }
  if (t >= 32 && t < 32+BATCH) {
    int b = t - 32;
    float R[9], tr[3];
    se3_exp_dev(igt_twist + b*6, R, tr);
    float* inv = igt_inv + b*12;
    for (int r = 0; r < 3; ++r) {
      inv[r*4+0] = R[0*3+r];
      inv[r*4+1] = R[1*3+r];
      inv[r*4+2] = R[2*3+r];
      inv[r*4+3] = -(R[0*3+r]*tr[0] + R[1*3+r]*tr[1] + R[2*3+r]*tr[2]);
    }
  }
}

// ---------------- weight packs (verified layouts) ----------------
// W3p: [nt][lev][ks3][lane][8], 4096 f16 (8 KB) per nt tile, linear.
__global__ void pack_w3_kernel(const float* __restrict__ W3, _Float16* __restrict__ P) {
  int i = blockIdx.x*256 + threadIdx.x;   // 128*1024
  int k = i >> 10, n = i & 1023;
  _Float16 hi, lo;
  split_f16s(W3[i], hi, lo);
  int nt = n >> 4, col = n & 15;
  int ks3 = k >> 5, rr = k & 31;
  int lane = (rr >> 3)*16 + col, jj = rr & 7;
  size_t base = (size_t)nt*4096;
  P[base + ((0*4 + ks3)*64 + lane)*8 + jj] = hi;
  P[base + ((1*4 + ks3)*64 + lane)*8 + jj] = lo;
}

__global__ void pack_w2_kernel(const float* __restrict__ W2,
                               _Float16* __restrict__ H, _Float16* __restrict__ L) {
  int i = blockIdx.x*256 + threadIdx.x;   // 64*128
  int k = i >> 7, n = i & 127;
  _Float16 hi, lo;
  split_f16s(W2[i], hi, lo);
  int nt2 = n >> 4, col = n & 15;
  int ks = k >> 5, rr = k & 31;
  int lane = (rr >> 3)*16 + col, jj = rr & 7;
  int dst = ((nt2*2 + ks)*64 + lane)*8 + jj;
  H[dst] = hi; L[dst] = lo;
}

// ---------------- shared encode pieces ----------------
__device__ __forceinline__ f32x4 zero4() {
  f32x4 z; z[0]=0.f; z[1]=0.f; z[2]=0.f; z[3]=0.f; return z;
}

// layer1 + layer2 (3-product) for one ptile -> layer-3 A fragments, via
// per-wave LDS relayout scratch (same-wave DS ordering, no barriers). No b3:
// b3 cancels exactly in J=(f0-fj)/dt and r=f1-f0, so it is dropped everywhere.
__device__ __forceinline__ void l12_ptile(
    float px, float py, float pz,
    const float* __restrict__ w1, const float* __restrict__ bb1,
    const _Float16* __restrict__ W2h, const _Float16* __restrict__ W2l,
    const float* __restrict__ b2,
    _Float16* scr, int l, int lm, int q,
    f16x8 (&A3h)[4], f16x8 (&A3l)[4]) {
  f16x8 A2h[2], A2l[2];
#pragma unroll
  for (int ks = 0; ks < 2; ++ks) {
    const int c0 = ks*32 + q*8;
    float wa[8], wb[8], wc[8], bv[8];
    *(float4*)&wa[0] = *(const float4*)(w1 + c0);
    *(float4*)&wa[4] = *(const float4*)(w1 + c0 + 4);
    *(float4*)&wb[0] = *(const float4*)(w1 + 64 + c0);
    *(float4*)&wb[4] = *(const float4*)(w1 + 64 + c0 + 4);
    *(float4*)&wc[0] = *(const float4*)(w1 + 128 + c0);
    *(float4*)&wc[4] = *(const float4*)(w1 + 128 + c0 + 4);
    *(float4*)&bv[0] = *(const float4*)(bb1 + c0);
    *(float4*)&bv[4] = *(const float4*)(bb1 + c0 + 4);
#pragma unroll
    for (int jj = 0; jj < 8; ++jj) {
      float h = fmaf(px, wa[jj], fmaf(py, wb[jj], fmaf(pz, wc[jj], bv[jj])));
      h = fmaxf(h, 0.f);
      _Float16 hi, lo;
      split_f16s(h, hi, lo);
      A2h[ks][jj] = hi; A2l[ks][jj] = lo;
    }
  }
#pragma unroll
  for (int nt2 = 0; nt2 < 8; ++nt2) {
    f32x4 acc = zero4();
#pragma unroll
    for (int ks = 0; ks < 2; ++ks) {
      const int base = ((nt2*2 + ks)*64 + l)*8;
      const f16x8 Bh = *(const f16x8*)(W2h + base);
      const f16x8 Bl = *(const f16x8*)(W2l + base);
      acc = MFMA16(A2l[ks], Bh, acc);
      acc = MFMA16(A2h[ks], Bl, acc);
      acc = MFMA16(A2h[ks], Bh, acc);
    }
    const int c2 = nt2*16 + lm;
    const float b2v = b2[c2];
    const int ks3 = c2 >> 5;
    const int k31 = c2 & 31;
    const int qw = k31 >> 3, jw = k31 & 7;
#pragma unroll
    for (int r = 0; r < 4; ++r) {
      const int mrow = q*4 + r;
      float h = fmaxf(acc[r]*INV16 + b2v, 0.f);
      _Float16 hi, lo;
      split_f16s(h, hi, lo);
      const int idx = (ks3*64 + qw*16 + mrow)*8 + jw;
      scr[idx] = hi;
      scr[2048 + idx] = lo;
    }
  }
#pragma unroll
  for (int ks3 = 0; ks3 < 4; ++ks3) {
    const int base = (ks3*64 + l)*8;
    A3h[ks3] = *(const f16x8*)&scr[base];
    A3l[ks3] = *(const f16x8*)&scr[2048 + base];
  }
}

// ---------------- BIG encode: 4 ptiles/wave (4 acc chains), LDS B dbuf,
// partial-max stores (no atomics). grid (8,7,8) x 256. ----------------
__global__ __launch_bounds__(256, 2) void encode_big(
    const float* __restrict__ pts, const float* __restrict__ mean,
    const float* __restrict__ W1e, const float* __restrict__ b1e,
    const _Float16* __restrict__ W2h, const _Float16* __restrict__ W2l,
    const _Float16* __restrict__ W3p, const float* __restrict__ b2,
    float* __restrict__ partial) {
  const int t = threadIdx.x;
  const int w = t >> 6, l = t & 63;
  const int lm = l & 15, q = l >> 4;
  const int pblk = blockIdx.x;
  const int j = blockIdx.y;
  const int b = blockIdx.z;

  __shared__ __align__(16) _Float16 smem[16384];   // 32 KB (scr, then B dbuf)

  const int ptbase = pblk*256 + w*64;
  float mx0 = mean[b*3+0], my0 = mean[b*3+1], mz0 = mean[b*3+2];
  const float* w1 = W1e + j*192;
  const float* bb1 = b1e + j*64;

  f16x8 A3h[4][4], A3l[4][4];
  _Float16* scr = smem + w*4096;
#pragma unroll
  for (int p = 0; p < 4; ++p) {
    const float* pp = pts + ((size_t)b*NPTS + ptbase + p*16 + lm)*3;
    l12_ptile(pp[0]-mx0, pp[1]-my0, pp[2]-mz0, w1, bb1, W2h, W2l, b2,
              scr, l, lm, q, A3h[p], A3l[p]);
  }
  __syncthreads();   // scr done; smem becomes B double buffer (2 x 8 KB)

  float* pout = partial + ((size_t)(j*BATCH + b)*32 + pblk*4 + w)*KF;
  {
    f16x8 s0 = *(const f16x8*)(W3p + t*8);
    f16x8 s1 = *(const f16x8*)(W3p + 2048 + t*8);
    *(f16x8*)&smem[t*8] = s0;
    *(f16x8*)&smem[2048 + t*8] = s1;
  }
  __syncthreads();

  for (int k = 0; k < 64; ++k) {
    const int cur = (k & 1)*4096;
    const int nxt = cur ^ 4096;
    f16x8 s0, s1;
    const int have_next = (k + 1 < 64);
    if (have_next) {
      const _Float16* src = W3p + (size_t)(k+1)*4096;
      s0 = *(const f16x8*)(src + t*8);
      s1 = *(const f16x8*)(src + 2048 + t*8);
    }
    f16x8 B[2][4];
#pragma unroll
    for (int lev = 0; lev < 2; ++lev)
#pragma unroll
      for (int ks = 0; ks < 4; ++ks)
        B[lev][ks] = *(const f16x8*)&smem[cur + ((lev*4 + ks)*64 + l)*8];

    f32x4 a[4] = {zero4(), zero4(), zero4(), zero4()};
#pragma unroll
    for (int ks = 0; ks < 4; ++ks) {
#pragma unroll
      for (int p = 0; p < 4; ++p) a[p] = MFMA16(A3l[p][ks], B[0][ks], a[p]);  // l*h
#pragma unroll
      for (int p = 0; p < 4; ++p) a[p] = MFMA16(A3h[p][ks], B[1][ks], a[p]);  // h*l
#pragma unroll
      for (int p = 0; p < 4; ++p) a[p] = MFMA16(A3h[p][ks], B[0][ks], a[p]);  // h*h
    }
    float mx = -INFINITY;
#pragma unroll
    for (int p = 0; p < 4; ++p)
#pragma unroll
      for (int r = 0; r < 4; ++r) mx = fmaxf(mx, a[p][r]);
    mx = fmaxf(mx, __shfl_xor(mx, 16, 64));
    mx = fmaxf(mx, __shfl_xor(mx, 32, 64));
    if (l < 16) pout[k*16 + lm] = mx*INV16;   // plain store, no atomic

    if (have_next) {
      *(f16x8*)&smem[nxt + t*8] = s0;
      *(f16x8*)&smem[nxt + 2048 + t*8] = s1;
    }
    __syncthreads();
  }
}

// reduce 32 partial slots -> feats[b][j][f]
__global__ void reduce_feats(const float* __restrict__ partial, float* __restrict__ feats) {
  int jb = blockIdx.x;            // j*BATCH + b
  int j = jb / BATCH, b = jb % BATCH;
  int t = threadIdx.x;
  const float* ps = partial + (size_t)jb*32*KF;
  for (int f = t; f < KF; f += 256) {
    float m = -INFINITY;
#pragma unroll 8
    for (int s = 0; s < 32; ++s) m = fmaxf(m, ps[s*KF + f]);
    feats[((size_t)b*7 + j)*KF + f] = m;
  }
}

// ---------------- LOOP encode: fused l1-l3, 1 ptile/wave, FG=4 ----------------
// grid (32, 4, 8) x 256 = 1024 blocks (~4/CU). Partial-max stores.
__global__ __launch_bounds__(256, 3) void encode_loop(
    const float* __restrict__ pts, const float* __restrict__ mean,
    const float* __restrict__ W1e, const float* __restrict__ b1e,
    const _Float16* __restrict__ W2h, const _Float16* __restrict__ W2l,
    const _Float16* __restrict__ W3p, const float* __restrict__ b2,
    float* __restrict__ partial2) {
  const int t = threadIdx.x;
  const int w = t >> 6, l = t & 63;
  const int lm = l & 15, q = l >> 4;
  const int pblk = blockIdx.x;
  const int fg = blockIdx.y;
  const int b = blockIdx.z;
  const int nt0 = fg*16;

  __shared__ __align__(16) _Float16 smem[16384];

  const int pt = pblk*64 + w*16;
  float mx0 = mean[b*3+0], my0 = mean[b*3+1], mz0 = mean[b*3+2];
  const float* w1 = W1e + b*192;
  const float* bb1 = b1e + b*64;

  f16x8 A3h[4], A3l[4];
  {
    const float* pp = pts + ((size_t)b*NPTS + pt + lm)*3;
    l12_ptile(pp[0]-mx0, pp[1]-my0, pp[2]-mz0, w1, bb1, W2h, W2l, b2,
              smem + w*4096, l, lm, q, A3h, A3l);
  }
  __syncthreads();

  float* pout = partial2 + ((size_t)b*128 + pblk*4 + w)*KF;
  {
    const _Float16* src = W3p + (size_t)nt0*4096;
    f16x8 s0 = *(const f16x8*)(src + t*8);
    f16x8 s1 = *(const f16x8*)(src + 2048 + t*8);
    *(f16x8*)&smem[t*8] = s0;
    *(f16x8*)&smem[2048 + t*8] = s1;
  }
  __syncthreads();

  for (int k = 0; k < 16; ++k) {
    const int cur = (k & 1)*4096;
    const int nxt = cur ^ 4096;
    f16x8 s0, s1;
    const int have_next = (k + 1 < 16);
    if (have_next) {
      const _Float16* src = W3p + (size_t)(nt0 + k + 1)*4096;
      s0 = *(const f16x8*)(src + t*8);
      s1 = *(const f16x8*)(src + 2048 + t*8);
    }
    f16x8 B[2][4];
#pragma unroll
    for (int lev = 0; lev < 2; ++lev)
#pragma unroll
      for (int ks = 0; ks < 4; ++ks)
        B[lev][ks] = *(const f16x8*)&smem[cur + ((lev*4 + ks)*64 + l)*8];

    f32x4 a = zero4();
#pragma unroll
    for (int ks = 0; ks < 4; ++ks) {
      a = MFMA16(A3l[ks], B[0][ks], a);
      a = MFMA16(A3h[ks], B[1][ks], a);
      a = MFMA16(A3h[ks], B[0][ks], a);
    }
    float mx = fmaxf(fmaxf(a[0], a[1]), fmaxf(a[2], a[3]));
    mx = fmaxf(mx, __shfl_xor(mx, 16, 64));
    mx = fmaxf(mx, __shfl_xor(mx, 32, 64));
    if (l < 16) pout[(nt0 + k)*16 + lm] = mx*INV16;

    if (have_next) {
      *(f16x8*)&smem[nxt + t*8] = s0;
      *(f16x8*)&smem[nxt + 2048 + t*8] = s1;
    }
    __syncthreads();
  }
}

// ---------------- pinv (verified; feats now sans-b3 — differences unchanged) ----------------
__global__ void pinv_kernel(const float* __restrict__ feats, const float* __restrict__ dt,
                            float* __restrict__ pinv) {
  int b = blockIdx.x, t = threadIdx.x;
  const float* f0 = feats + (size_t)b*7*KF;
  const float* fj = f0 + KF;
  float idt[6];
#pragma unroll
  for (int i = 0; i < 6; ++i) idt[i] = 1.f / dt[i];
  float H[21];
#pragma unroll
  for (int i = 0; i < 21; ++i) H[i] = 0.f;
  for (int k = t; k < KF; k += 256) {
    float f0k = f0[k];
    float Jk[6];
#pragma unroll
    for (int i = 0; i < 6; ++i) Jk[i] = (f0k - fj[i*KF + k]) * idt[i];
    int idx = 0;
#pragma unroll
    for (int i = 0; i < 6; ++i)
#pragma unroll
      for (int jj = i; jj < 6; ++jj) H[idx++] += Jk[i]*Jk[jj];
  }
  __shared__ float red[256*21];
#pragma unroll
  for (int i = 0; i < 21; ++i) red[t*21+i] = H[i];
  __syncthreads();
  for (int s = 128; s > 0; s >>= 1) {
    if (t < s)
      for (int i = 0; i < 21; ++i) red[t*21+i] += red[(t+s)*21+i];
    __syncthreads();
  }
  __shared__ float s_hinv[36];
  if (t == 0) {
    double A[6][12];
    int idx = 0;
    for (int i = 0; i < 6; ++i)
      for (int jj = i; jj < 6; ++jj) { A[i][jj] = red[idx]; A[jj][i] = red[idx]; idx++; }
    for (int i = 0; i < 6; ++i)
      for (int jj = 0; jj < 6; ++jj) A[i][6+jj] = (i == jj) ? 1.0 : 0.0;
    for (int col = 0; col < 6; ++col) {
      int piv = col; double best = fabs(A[col][col]);
      for (int r2 = col+1; r2 < 6; ++r2) {
        double v = fabs(A[r2][col]);
        if (v > best) { best = v; piv = r2; }
      }
      if (piv != col)
        for (int jj = 0; jj < 12; ++jj) { double tmp = A[col][jj]; A[col][jj] = A[piv][jj]; A[piv][jj] = tmp; }
      double inv = 1.0 / A[col][col];
      for (int jj = 0; jj < 12; ++jj) A[col][jj] *= inv;
      for (int r2 = 0; r2 < 6; ++r2) if (r2 != col) {
        double f = A[r2][col];
        for (int jj = 0; jj < 12; ++jj) A[r2][jj] -= f * A[col][jj];
      }
    }
    for (int i = 0; i < 6; ++i)
      for (int jj = 0; jj < 6; ++jj) s_hinv[i*6+jj] = (float)A[i][6+jj];
  }
  __syncthreads();
  for (int k = t; k < KF; k += 256) {
    float f0k = f0[k];
    float Jk[6];
#pragma unroll
    for (int i = 0; i < 6; ++i) Jk[i] = (f0k - fj[i*KF + k]) * idt[i];
#pragma unroll
    for (int i = 0; i < 6; ++i) {
      float s = 0.f;
#pragma unroll
      for (int jj = 0; jj < 6; ++jj) s += s_hinv[i*6+jj] * Jk[jj];
      pinv[((size_t)b*6 + i)*KF + k] = s;
    }
  }
}

// update: fuses the 128-slot partial max (f1) with the GN step.
__global__ void update_kernel(const float* __restrict__ feats, const float* __restrict__ part2,
                              const float* __restrict__ pinv, float* __restrict__ g_buf,
                              const float* __restrict__ W1, const float* __restrict__ b1,
                              float* __restrict__ W1effL, float* __restrict__ b1effL,
                              float* __restrict__ r_out,
                              const float* __restrict__ mean_tgt, const float* __restrict__ mean_src,
                              float* __restrict__ est_g, int final_it) {
  int b = blockIdx.x, t = threadIdx.x;
  const float* f0 = feats + (size_t)b*7*KF;
  const float* ps = part2 + (size_t)b*128*KF;
  float acc[6] = {0.f,0.f,0.f,0.f,0.f,0.f};
  for (int k = t; k < KF; k += 256) {
    float m = -INFINITY;
#pragma unroll 8
    for (int s = 0; s < 128; ++s) m = fmaxf(m, ps[(size_t)s*KF + k]);
    float r = m - f0[k];
    r_out[(size_t)b*KF + k] = r;
#pragma unroll
    for (int i = 0; i < 6; ++i) acc[i] += pinv[((size_t)b*6+i)*KF + k] * r;
  }
  __shared__ float red[256*6];
#pragma unroll
  for (int i = 0; i < 6; ++i) red[t*6+i] = acc[i];
  __syncthreads();
  for (int s = 128; s > 0; s >>= 1) {
    if (t < s)
      for (int i = 0; i < 6; ++i) red[t*6+i] += red[(t+s)*6+i];
    __syncthreads();
  }
  __shared__ float s_g[16];
  if (t == 0) {
    float dx[6];
#pragma unroll
    for (int i = 0; i < 6; ++i) dx[i] = -red[i];
    float R[9], p[3];
    se3_exp_dev(dx, R, p);
    float* g = g_buf + b*16;
    float gn[16];
    for (int r2 = 0; r2 < 3; ++r2)
      for (int c = 0; c < 4; ++c)
        gn[r2*4+c] = R[r2*3+0]*g[c] + R[r2*3+1]*g[4+c] + R[r2*3+2]*g[8+c] + p[r2]*g[12+c];
    gn[12] = 0.f; gn[13] = 0.f; gn[14] = 0.f; gn[15] = 1.f;
    for (int i = 0; i < 16; ++i) { g[i] = gn[i]; s_g[i] = gn[i]; }
    if (final_it) {
      const float* p0m = mean_tgt + b*3;
      const float* p1m = mean_src + b*3;
      float* e = est_g + b*12;
      for (int r2 = 0; r2 < 3; ++r2) {
        e[r2*4+0] = gn[r2*4+0];
        e[r2*4+1] = gn[r2*4+1];
        e[r2*4+2] = gn[r2*4+2];
        e[r2*4+3] = gn[r2*4+3]
                  - (gn[r2*4+0]*p1m[0] + gn[r2*4+1]*p1m[1] + gn[r2*4+2]*p1m[2])
                  + p0m[r2];
      }
    }
  }
  __syncthreads();
  if (!final_it) {
    for (int i = t; i < 192; i += 256) {
      int d = i >> 6, c = i & 63;
      W1effL[b*192 + i] = s_g[0*4+d]*W1[c] + s_g[1*4+d]*W1[64+c] + s_g[2*4+d]*W1[128+c];
    }
    for (int i = t; i < 64; i += 256)
      b1effL[b*64 + i] = b1[i] + s_g[3]*W1[i] + s_g[7]*W1[64+i] + s_g[11]*W1[128+i];
  }
}

__global__ void loss_kernel(const float* __restrict__ p_src, const float* __restrict__ est_g,
                            const float* __restrict__ igt_inv, float* __restrict__ loss_out) {
  int b = blockIdx.y, tile = blockIdx.x, t = threadIdx.x;
  int n = tile*256 + t;
  const float* e = est_g + b*12;
  const float* v = igt_inv + b*12;
  const float* p = p_src + ((size_t)b*NPTS + n)*3;
  float px = p[0], py = p[1], pz = p[2];
  float s = 0.f;
#pragma unroll
  for (int r2 = 0; r2 < 3; ++r2) {
    float d1 = e[r2*4+0]*px + e[r2*4+1]*py + e[r2*4+2]*pz + e[r2*4+3];
    float d2 = v[r2*4+0]*px + v[r2*4+1]*py + v[r2*4+2]*pz + v[r2*4+3];
    s += fabsf(d1 - d2);
  }
  __shared__ float red[256];
  red[t] = s;
  __syncthreads();
  for (int st = 128; st > 0; st >>= 1) {
    if (t < st) red[t] += red[t+st];
    __syncthreads();
  }
  if (t == 0) atomicAdd(loss_out, red[0] * (1.f/((float)BATCH*NPTS*3)));
}

// ---------------- launcher ----------------
extern "C" void kernel_launch(void* const* d_in, const int* in_sizes, int n_in,
                              void* d_out, int out_size, void* d_ws, size_t ws_size,
                              hipStream_t stream) {
  const float* p_src     = (const float*)d_in[0];
  const float* p_tgt     = (const float*)d_in[1];
  const float* igt_twist = (const float*)d_in[2];
  const float* dt        = (const float*)d_in[3];
  const float* W1        = (const float*)d_in[4];
  const float* b1        = (const float*)d_in[5];
  const float* W2        = (const float*)d_in[6];
  const float* b2        = (const float*)d_in[7];
  const float* W3        = (const float*)d_in[8];
  float* out = (float*)d_out;

  float* ws = (float*)d_ws;
  float* mean_tgt = ws;  ws += 32;
  float* mean_src = ws;  ws += 32;
  float* W1eff7   = ws;  ws += 7*192;
  float* b1eff7   = ws;  ws += 7*64;
  float* feats    = ws;  ws += BATCH*7*KF;
  float* W1effL   = ws;  ws += BATCH*192;
  float* b1effL   = ws;  ws += BATCH*64;
  float* g_buf    = ws;  ws += BATCH*16;
  float* pinvb    = ws;  ws += BATCH*6*KF;
  float* igt_inv  = ws;  ws += 96;
  float* est_g    = ws;  ws += 96;
  _Float16* W2h = (_Float16*)ws;  ws += 8192/2;
  _Float16* W2l = (_Float16*)ws;  ws += 8192/2;
  _Float16* W3p = (_Float16*)ws;  ws += 262144/2;     // 64 tiles x 8 KB
  float* partialB = ws;  ws += 56*32*KF;              // big-encode partial maxes (7.3 MB)
  float* partial2 = ws;  ws += BATCH*128*KF;          // loop-encode partial maxes (4 MB)

  float* r_out    = out;
  float* loss_out = out + BATCH*KF;

  means_kernel<<<dim3(BATCH*2), 256, 0, stream>>>(p_tgt, p_src, mean_tgt, mean_src);
  setup_kernel<<<1, 256, 0, stream>>>(dt, W1, b1, igt_twist, W1eff7, b1eff7,
                                      W1effL, b1effL, g_buf, igt_inv, loss_out);
  pack_w2_kernel<<<dim3(8192/256), 256, 0, stream>>>(W2, W2h, W2l);
  pack_w3_kernel<<<dim3(131072/256), 256, 0, stream>>>(W3, W3p);

  encode_big<<<dim3(8, 7, BATCH), 256, 0, stream>>>(
      p_tgt, mean_tgt, W1eff7, b1eff7, W2h, W2l, W3p, b2, partialB);
  reduce_feats<<<dim3(7*BATCH), 256, 0, stream>>>(partialB, feats);
  pinv_kernel<<<dim3(BATCH), 256, 0, stream>>>(feats, dt, pinvb);

  for (int it = 0; it < 5; ++it) {
    encode_loop<<<dim3(32, 4, BATCH), 256, 0, stream>>>(
        p_src, mean_src, W1effL, b1effL, W2h, W2l, W3p, b2, partial2);
    update_kernel<<<dim3(BATCH), 256, 0, stream>>>(
        feats, partial2, pinvb, g_buf, W1, b1, W1effL, b1effL, r_out,
        mean_tgt, mean_src, est_g, (it == 4) ? 1 : 0);
  }
  loss_kernel<<<dim3(NPTS/256, BATCH), 256, 0, stream>>>(p_src, est_g, igt_inv, loss_out);
}

// Round 10
// 314.663 us; speedup vs baseline: 2.3772x; 2.3772x over previous
//
#include <hip/hip_runtime.h>
#include <math.h>

#define BATCH 8
#define NPTS 2048
#define KF 1024

typedef _Float16 f16x8 __attribute__((ext_vector_type(8)));
typedef float f32x4 __attribute__((ext_vector_type(4)));

// 16x16x32 layouts HW-verified (m89/m91/m97/m120):
//  A: lane holds A[m=lane&15][k=(lane>>4)*8+j]
//  B: lane holds B[k=(lane>>4)*8+j][n=lane&15]
//  C/D: lane,reg holds C[row=(lane>>4)*4+reg][col=lane&15]
#define MFMA16(a,b,c) __builtin_amdgcn_mfma_f32_16x16x32_f16((a),(b),(c),0,0,0)

#define FSCALE 256.0f
#define INV16  (1.0f/65536.0f)

// fp16 2-way split of (x*256); 3 products (hh, hl, lh), ll dropped (~4e-4 on r).
__device__ __forceinline__ void split_f16s(float x, _Float16& hi, _Float16& lo) {
  float xs = x * FSCALE;
  hi = (_Float16)xs;
  lo = (_Float16)(xs - (float)hi);
}

// ---------------- misc device helpers ----------------
__device__ __forceinline__ void mat3mul(const float* A, const float* Bm, float* C) {
#pragma unroll
  for (int i = 0; i < 3; ++i)
#pragma unroll
    for (int j = 0; j < 3; ++j)
      C[i*3+j] = A[i*3+0]*Bm[0*3+j] + A[i*3+1]*Bm[1*3+j] + A[i*3+2]*Bm[2*3+j];
}

__device__ void se3_exp_dev(const float* x, float* R, float* p) {
  float wx = x[0], wy = x[1], wz = x[2];
  float vx = x[3], vy = x[4], vz = x[5];
  float t2 = wx*wx + wy*wy + wz*wz;
  float t = sqrtf(t2);
  float A, Bc, Cc;
  if (t < 1e-6f) {
    A  = 1.f - t2*(1.f/6.f);
    Bc = 0.5f - t2*(1.f/24.f);
    Cc = (1.f/6.f) - t2*(1.f/120.f);
  } else {
    float s = sinf(t), c = cosf(t);
    A  = s / t;
    Bc = (1.f - c) / t2;
    Cc = (t - s) / (t2 * t);
  }
  float W[9]  = {0.f, -wz, wy,  wz, 0.f, -wx,  -wy, wx, 0.f};
  float W2[9];
  mat3mul(W, W, W2);
#pragma unroll
  for (int i = 0; i < 9; ++i) {
    float I = (i == 0 || i == 4 || i == 8) ? 1.f : 0.f;
    R[i] = I + A*W[i] + Bc*W2[i];
  }
  float V[9];
#pragma unroll
  for (int i = 0; i < 9; ++i) {
    float I = (i == 0 || i == 4 || i == 8) ? 1.f : 0.f;
    V[i] = I + Bc*W[i] + Cc*W2[i];
  }
  p[0] = V[0]*vx + V[1]*vy + V[2]*vz;
  p[1] = V[3]*vx + V[4]*vy + V[5]*vz;
  p[2] = V[6]*vx + V[7]*vy + V[8]*vz;
}

// ---------------- small kernels (verified) ----------------
__global__ void means_kernel(const float* __restrict__ tgt, const float* __restrict__ src,
                             float* __restrict__ mean_tgt, float* __restrict__ mean_src) {
  int which = blockIdx.x & 1, b = blockIdx.x >> 1;
  const float* p = (which ? src : tgt) + (size_t)b*NPTS*3;
  float* m = (which ? mean_src : mean_tgt) + b*3;
  int t = threadIdx.x;
  float s0 = 0.f, s1 = 0.f, s2 = 0.f;
  for (int i = t; i < NPTS; i += 256) {
    s0 += p[i*3+0]; s1 += p[i*3+1]; s2 += p[i*3+2];
  }
  __shared__ float red[256][3];
  red[t][0] = s0; red[t][1] = s1; red[t][2] = s2;
  __syncthreads();
  for (int s = 128; s > 0; s >>= 1) {
    if (t < s) { red[t][0] += red[t+s][0]; red[t][1] += red[t+s][1]; red[t][2] += red[t+s][2]; }
    __syncthreads();
  }
  if (t == 0) {
    m[0] = red[0][0] * (1.f/NPTS);
    m[1] = red[0][1] * (1.f/NPTS);
    m[2] = red[0][2] * (1.f/NPTS);
  }
}

__global__ void setup_kernel(const float* __restrict__ dt, const float* __restrict__ W1,
                             const float* __restrict__ b1, const float* __restrict__ igt_twist,
                             float* __restrict__ W1eff7, float* __restrict__ b1eff7,
                             float* __restrict__ W1effL, float* __restrict__ b1effL,
                             float* __restrict__ g_buf, float* __restrict__ igt_inv,
                             float* __restrict__ loss_out) {
  int t = threadIdx.x;
  for (int i = t; i < BATCH*192;  i += 256) W1effL[i] = W1[i % 192];
  for (int i = t; i < BATCH*64;   i += 256) b1effL[i] = b1[i & 63];
  if (t < 192) W1eff7[t] = W1[t];
  if (t < 64)  b1eff7[t] = b1[t];
  if (t < BATCH*16) {
    int i = t & 15;
    g_buf[t] = (i == 0 || i == 5 || i == 10 || i == 15) ? 1.f : 0.f;
  }
  if (t == 0) *loss_out = 0.f;
  if (t < 6) {
    float tw[6] = {0.f,0.f,0.f,0.f,0.f,0.f};
    tw[t] = -dt[t];
    float R[9], tr[3];
    se3_exp_dev(tw, R, tr);
    float* Wd = W1eff7 + (t+1)*192;
    for (int d = 0; d < 3; ++d)
      for (int c = 0; c < 64; ++c)
        Wd[d*64+c] = R[0*3+d]*W1[c] + R[1*3+d]*W1[64+c] + R[2*3+d]*W1[128+c];
    float* bd = b1eff7 + (t+1)*64;
    for (int c = 0; c < 64; ++c)
      bd[c] = b1[c] + tr[0]*W1[c] + tr[1]*W1[64+c] + tr[2]*W1[128+c];
  }
  if (t >= 32 && t < 32+BATCH) {
    int b = t - 32;
    float R[9], tr[3];
    se3_exp_dev(igt_twist + b*6, R, tr);
    float* inv = igt_inv + b*12;
    for (int r = 0; r < 3; ++r) {
      inv[r*4+0] = R[0*3+r];
      inv[r*4+1] = R[1*3+r];
      inv[r*4+2] = R[2*3+r];
      inv[r*4+3] = -(R[0*3+r]*tr[0] + R[1*3+r]*tr[1] + R[2*3+r]*tr[2]);
    }
  }
}

// ---------------- weight packs (verified layouts) ----------------
// W3p: [nt][lev][ks3][lane][8], 4096 f16 (8 KB) per nt tile, linear.
__global__ void pack_w3_kernel(const float* __restrict__ W3, _Float16* __restrict__ P) {
  int i = blockIdx.x*256 + threadIdx.x;   // 128*1024
  int k = i >> 10, n = i & 1023;
  _Float16 hi, lo;
  split_f16s(W3[i], hi, lo);
  int nt = n >> 4, col = n & 15;
  int ks3 = k >> 5, rr = k & 31;
  int lane = (rr >> 3)*16 + col, jj = rr & 7;
  size_t base = (size_t)nt*4096;
  P[base + ((0*4 + ks3)*64 + lane)*8 + jj] = hi;
  P[base + ((1*4 + ks3)*64 + lane)*8 + jj] = lo;
}

__global__ void pack_w2_kernel(const float* __restrict__ W2,
                               _Float16* __restrict__ H, _Float16* __restrict__ L) {
  int i = blockIdx.x*256 + threadIdx.x;   // 64*128
  int k = i >> 7, n = i & 127;
  _Float16 hi, lo;
  split_f16s(W2[i], hi, lo);
  int nt2 = n >> 4, col = n & 15;
  int ks = k >> 5, rr = k & 31;
  int lane = (rr >> 3)*16 + col, jj = rr & 7;
  int dst = ((nt2*2 + ks)*64 + lane)*8 + jj;
  H[dst] = hi; L[dst] = lo;
}

// ---------------- shared encode pieces ----------------
__device__ __forceinline__ f32x4 zero4() {
  f32x4 z; z[0]=0.f; z[1]=0.f; z[2]=0.f; z[3]=0.f; return z;
}

// layer1 + layer2 (3-product) for one ptile -> layer-3 A fragments, via
// per-wave LDS relayout scratch. b3 dropped everywhere (cancels in J and r).
__device__ __forceinline__ void l12_ptile(
    float px, float py, float pz,
    const float* __restrict__ w1, const float* __restrict__ bb1,
    const _Float16* __restrict__ W2h, const _Float16* __restrict__ W2l,
    const float* __restrict__ b2,
    _Float16* scr, int l, int lm, int q,
    f16x8 (&A3h)[4], f16x8 (&A3l)[4]) {
  f16x8 A2h[2], A2l[2];
#pragma unroll
  for (int ks = 0; ks < 2; ++ks) {
    const int c0 = ks*32 + q*8;
    float wa[8], wb[8], wc[8], bv[8];
    *(float4*)&wa[0] = *(const float4*)(w1 + c0);
    *(float4*)&wa[4] = *(const float4*)(w1 + c0 + 4);
    *(float4*)&wb[0] = *(const float4*)(w1 + 64 + c0);
    *(float4*)&wb[4] = *(const float4*)(w1 + 64 + c0 + 4);
    *(float4*)&wc[0] = *(const float4*)(w1 + 128 + c0);
    *(float4*)&wc[4] = *(const float4*)(w1 + 128 + c0 + 4);
    *(float4*)&bv[0] = *(const float4*)(bb1 + c0);
    *(float4*)&bv[4] = *(const float4*)(bb1 + c0 + 4);
#pragma unroll
    for (int jj = 0; jj < 8; ++jj) {
      float h = fmaf(px, wa[jj], fmaf(py, wb[jj], fmaf(pz, wc[jj], bv[jj])));
      h = fmaxf(h, 0.f);
      _Float16 hi, lo;
      split_f16s(h, hi, lo);
      A2h[ks][jj] = hi; A2l[ks][jj] = lo;
    }
  }
#pragma unroll
  for (int nt2 = 0; nt2 < 8; ++nt2) {
    f32x4 acc = zero4();
#pragma unroll
    for (int ks = 0; ks < 2; ++ks) {
      const int base = ((nt2*2 + ks)*64 + l)*8;
      const f16x8 Bh = *(const f16x8*)(W2h + base);
      const f16x8 Bl = *(const f16x8*)(W2l + base);
      acc = MFMA16(A2l[ks], Bh, acc);
      acc = MFMA16(A2h[ks], Bl, acc);
      acc = MFMA16(A2h[ks], Bh, acc);
    }
    const int c2 = nt2*16 + lm;
    const float b2v = b2[c2];
    const int ks3 = c2 >> 5;
    const int k31 = c2 & 31;
    const int qw = k31 >> 3, jw = k31 & 7;
#pragma unroll
    for (int r = 0; r < 4; ++r) {
      const int mrow = q*4 + r;
      float h = fmaxf(acc[r]*INV16 + b2v, 0.f);
      _Float16 hi, lo;
      split_f16s(h, hi, lo);
      const int idx = (ks3*64 + qw*16 + mrow)*8 + jw;
      scr[idx] = hi;
      scr[2048 + idx] = lo;
    }
  }
#pragma unroll
  for (int ks3 = 0; ks3 < 4; ++ks3) {
    const int base = (ks3*64 + l)*8;
    A3h[ks3] = *(const f16x8*)&scr[base];
    A3l[ks3] = *(const f16x8*)&scr[2048 + base];
  }
}

// ---------------- BIG encode: 4 ptiles/wave, LDS B dbuf, in-block cross-wave
// max -> 8 partial slots (one per pblk). grid (8,7,8) x 256. ----------------
__global__ __launch_bounds__(256, 2) void encode_big(
    const float* __restrict__ pts, const float* __restrict__ mean,
    const float* __restrict__ W1e, const float* __restrict__ b1e,
    const _Float16* __restrict__ W2h, const _Float16* __restrict__ W2l,
    const _Float16* __restrict__ W3p, const float* __restrict__ b2,
    float* __restrict__ partial) {
  const int t = threadIdx.x;
  const int w = t >> 6, l = t & 63;
  const int lm = l & 15, q = l >> 4;
  const int pblk = blockIdx.x;
  const int j = blockIdx.y;
  const int b = blockIdx.z;

  __shared__ __align__(16) _Float16 smem[16384];   // 32 KB

  const int ptbase = pblk*256 + w*64;
  float mx0 = mean[b*3+0], my0 = mean[b*3+1], mz0 = mean[b*3+2];
  const float* w1 = W1e + j*192;
  const float* bb1 = b1e + j*64;

  f16x8 A3h[4][4], A3l[4][4];
  _Float16* scr = smem + w*4096;
#pragma unroll
  for (int p = 0; p < 4; ++p) {
    const float* pp = pts + ((size_t)b*NPTS + ptbase + p*16 + lm)*3;
    l12_ptile(pp[0]-mx0, pp[1]-my0, pp[2]-mz0, w1, bb1, W2h, W2l, b2,
              scr, l, lm, q, A3h[p], A3l[p]);
  }
  __syncthreads();   // scr done; smem: [0,16KB) B dbuf, [16KB,32KB) maxbuf

  float* maxb = (float*)(smem + 8192);   // float[4][1024]
  {
    f16x8 s0 = *(const f16x8*)(W3p + t*8);
    f16x8 s1 = *(const f16x8*)(W3p + 2048 + t*8);
    *(f16x8*)&smem[t*8] = s0;
    *(f16x8*)&smem[2048 + t*8] = s1;
  }
  __syncthreads();

  for (int k = 0; k < 64; ++k) {
    const int cur = (k & 1)*4096;
    const int nxt = cur ^ 4096;
    f16x8 s0, s1;
    const int have_next = (k + 1 < 64);
    if (have_next) {
      const _Float16* src = W3p + (size_t)(k+1)*4096;
      s0 = *(const f16x8*)(src + t*8);
      s1 = *(const f16x8*)(src + 2048 + t*8);
    }
    f16x8 B[2][4];
#pragma unroll
    for (int lev = 0; lev < 2; ++lev)
#pragma unroll
      for (int ks = 0; ks < 4; ++ks)
        B[lev][ks] = *(const f16x8*)&smem[cur + ((lev*4 + ks)*64 + l)*8];

    f32x4 a[4] = {zero4(), zero4(), zero4(), zero4()};
#pragma unroll
    for (int ks = 0; ks < 4; ++ks) {
#pragma unroll
      for (int p = 0; p < 4; ++p) a[p] = MFMA16(A3l[p][ks], B[0][ks], a[p]);  // l*h
#pragma unroll
      for (int p = 0; p < 4; ++p) a[p] = MFMA16(A3h[p][ks], B[1][ks], a[p]);  // h*l
#pragma unroll
      for (int p = 0; p < 4; ++p) a[p] = MFMA16(A3h[p][ks], B[0][ks], a[p]);  // h*h
    }
    float mx = -INFINITY;
#pragma unroll
    for (int p = 0; p < 4; ++p)
#pragma unroll
      for (int r = 0; r < 4; ++r) mx = fmaxf(mx, a[p][r]);
    mx = fmaxf(mx, __shfl_xor(mx, 16, 64));
    mx = fmaxf(mx, __shfl_xor(mx, 32, 64));
    if (l < 16) maxb[w*1024 + k*16 + lm] = mx;

    if (have_next) {
      *(f16x8*)&smem[nxt + t*8] = s0;
      *(f16x8*)&smem[nxt + 2048 + t*8] = s1;
    }
    __syncthreads();
  }
  // cross-wave max -> one partial slot per block
  float* pout = partial + ((size_t)(j*BATCH + b)*8 + pblk)*KF;
  for (int f = t; f < KF; f += 256) {
    float m = fmaxf(fmaxf(maxb[f], maxb[1024+f]), fmaxf(maxb[2048+f], maxb[3072+f]));
    pout[f] = m*INV16;
  }
}

// ---------------- pinv: grid(8) x 1024 thr (1 k/thread, 16 waves).
// Fuses the 8-slot partial reduce (f0 + 6 twists), H build, f64 inverse,
// and pinv write. Also emits f0 for update. ----------------
__global__ __launch_bounds__(1024) void pinv_kernel(
    const float* __restrict__ partialB, const float* __restrict__ dt,
    float* __restrict__ pinvb, float* __restrict__ feats0) {
  const int b = blockIdx.x, t = threadIdx.x;   // t = feature k
  float fv[7];
#pragma unroll
  for (int j = 0; j < 7; ++j) {
    const float* ps = partialB + ((size_t)(j*BATCH + b)*8)*KF + t;
    float m = ps[0];
#pragma unroll
    for (int s = 1; s < 8; ++s) m = fmaxf(m, ps[(size_t)s*KF]);
    fv[j] = m;
  }
  feats0[(size_t)b*KF + t] = fv[0];
  float Jk[6];
#pragma unroll
  for (int i = 0; i < 6; ++i) Jk[i] = (fv[0] - fv[1+i]) / dt[i];
  float H[21];
  {
    int idx = 0;
#pragma unroll
    for (int i = 0; i < 6; ++i)
#pragma unroll
      for (int jj = i; jj < 6; ++jj) H[idx++] = Jk[i]*Jk[jj];
  }
#pragma unroll
  for (int i = 0; i < 21; ++i) {
    float v = H[i];
#pragma unroll
    for (int o = 1; o < 64; o <<= 1) v += __shfl_xor(v, o, 64);
    H[i] = v;
  }
  __shared__ float hred[16*21];
  __shared__ float s_hinv[36];
  const int wv = t >> 6, ln = t & 63;
  if (ln == 0)
#pragma unroll
    for (int i = 0; i < 21; ++i) hred[wv*21 + i] = H[i];
  __syncthreads();
  if (t == 0) {
    double A[6][12];
    float Ht[21];
    for (int i = 0; i < 21; ++i) {
      float s = 0.f;
      for (int w2 = 0; w2 < 16; ++w2) s += hred[w2*21 + i];
      Ht[i] = s;
    }
    int idx = 0;
    for (int i = 0; i < 6; ++i)
      for (int jj = i; jj < 6; ++jj) { A[i][jj] = Ht[idx]; A[jj][i] = Ht[idx]; idx++; }
    for (int i = 0; i < 6; ++i)
      for (int jj = 0; jj < 6; ++jj) A[i][6+jj] = (i == jj) ? 1.0 : 0.0;
    for (int col = 0; col < 6; ++col) {
      int piv = col; double best = fabs(A[col][col]);
      for (int r2 = col+1; r2 < 6; ++r2) {
        double v = fabs(A[r2][col]);
        if (v > best) { best = v; piv = r2; }
      }
      if (piv != col)
        for (int jj = 0; jj < 12; ++jj) { double tmp = A[col][jj]; A[col][jj] = A[piv][jj]; A[piv][jj] = tmp; }
      double inv = 1.0 / A[col][col];
      for (int jj = 0; jj < 12; ++jj) A[col][jj] *= inv;
      for (int r2 = 0; r2 < 6; ++r2) if (r2 != col) {
        double f = A[r2][col];
        for (int jj = 0; jj < 12; ++jj) A[r2][jj] -= f * A[col][jj];
      }
    }
    for (int i = 0; i < 6; ++i)
      for (int jj = 0; jj < 6; ++jj) s_hinv[i*6+jj] = (float)A[i][6+jj];
  }
  __syncthreads();
#pragma unroll
  for (int i = 0; i < 6; ++i) {
    float s = 0.f;
#pragma unroll
    for (int jj = 0; jj < 6; ++jj) s += s_hinv[i*6+jj] * Jk[jj];
    pinvb[((size_t)b*6 + i)*KF + t] = s;
  }
}

// ---------------- LOOP encode: fused l1-l3, cross-wave max -> 32 slots ----------------
// grid (32, 4, 8) x 256; block writes its 256-feature stripe of slot pblk.
__global__ __launch_bounds__(256, 3) void encode_loop(
    const float* __restrict__ pts, const float* __restrict__ mean,
    const float* __restrict__ W1e, const float* __restrict__ b1e,
    const _Float16* __restrict__ W2h, const _Float16* __restrict__ W2l,
    const _Float16* __restrict__ W3p, const float* __restrict__ b2,
    float* __restrict__ partial2) {
  const int t = threadIdx.x;
  const int w = t >> 6, l = t & 63;
  const int lm = l & 15, q = l >> 4;
  const int pblk = blockIdx.x;
  const int fg = blockIdx.y;
  const int b = blockIdx.z;
  const int nt0 = fg*16;

  __shared__ __align__(16) _Float16 smem[16384];

  const int pt = pblk*64 + w*16;
  float mx0 = mean[b*3+0], my0 = mean[b*3+1], mz0 = mean[b*3+2];
  const float* w1 = W1e + b*192;
  const float* bb1 = b1e + b*64;

  f16x8 A3h[4], A3l[4];
  {
    const float* pp = pts + ((size_t)b*NPTS + pt + lm)*3;
    l12_ptile(pp[0]-mx0, pp[1]-my0, pp[2]-mz0, w1, bb1, W2h, W2l, b2,
              smem + w*4096, l, lm, q, A3h, A3l);
  }
  __syncthreads();

  float* maxb = (float*)(smem + 8192);   // float[4][256]
  {
    const _Float16* src = W3p + (size_t)nt0*4096;
    f16x8 s0 = *(const f16x8*)(src + t*8);
    f16x8 s1 = *(const f16x8*)(src + 2048 + t*8);
    *(f16x8*)&smem[t*8] = s0;
    *(f16x8*)&smem[2048 + t*8] = s1;
  }
  __syncthreads();

  for (int k = 0; k < 16; ++k) {
    const int cur = (k & 1)*4096;
    const int nxt = cur ^ 4096;
    f16x8 s0, s1;
    const int have_next = (k + 1 < 16);
    if (have_next) {
      const _Float16* src = W3p + (size_t)(nt0 + k + 1)*4096;
      s0 = *(const f16x8*)(src + t*8);
      s1 = *(const f16x8*)(src + 2048 + t*8);
    }
    f16x8 B[2][4];
#pragma unroll
    for (int lev = 0; lev < 2; ++lev)
#pragma unroll
      for (int ks = 0; ks < 4; ++ks)
        B[lev][ks] = *(const f16x8*)&smem[cur + ((lev*4 + ks)*64 + l)*8];

    f32x4 a = zero4();
#pragma unroll
    for (int ks = 0; ks < 4; ++ks) {
      a = MFMA16(A3l[ks], B[0][ks], a);
      a = MFMA16(A3h[ks], B[1][ks], a);
      a = MFMA16(A3h[ks], B[0][ks], a);
    }
    float mx = fmaxf(fmaxf(a[0], a[1]), fmaxf(a[2], a[3]));
    mx = fmaxf(mx, __shfl_xor(mx, 16, 64));
    mx = fmaxf(mx, __shfl_xor(mx, 32, 64));
    if (l < 16) maxb[w*256 + k*16 + lm] = mx;

    if (have_next) {
      *(f16x8*)&smem[nxt + t*8] = s0;
      *(f16x8*)&smem[nxt + 2048 + t*8] = s1;
    }
    __syncthreads();
  }
  if (t < 256) {
    float m = fmaxf(fmaxf(maxb[t], maxb[256+t]), fmaxf(maxb[512+t], maxb[768+t]));
    partial2[((size_t)b*32 + pblk)*KF + fg*256 + t] = m*INV16;
  }
}

// ---------------- update: grid(8) x 1024 thr (1 feature/thread, 16 waves).
// 32-slot max -> f1, r, shfl-reduced 6-dot, thread-0 GN step. ----------------
__global__ __launch_bounds__(1024) void update_kernel(
    const float* __restrict__ feats0, const float* __restrict__ partial2,
    const float* __restrict__ pinv, float* __restrict__ g_buf,
    const float* __restrict__ W1, const float* __restrict__ b1,
    float* __restrict__ W1effL, float* __restrict__ b1effL,
    float* __restrict__ r_out,
    const float* __restrict__ mean_tgt, const float* __restrict__ mean_src,
    float* __restrict__ est_g, int final_it) {
  const int b = blockIdx.x, t = threadIdx.x;
  const float* ps = partial2 + (size_t)b*32*KF + t;
  float m = ps[0];
#pragma unroll
  for (int s = 1; s < 32; ++s) m = fmaxf(m, ps[(size_t)s*KF]);
  float r = m - feats0[(size_t)b*KF + t];
  r_out[(size_t)b*KF + t] = r;
  float acc[6];
#pragma unroll
  for (int i = 0; i < 6; ++i) acc[i] = pinv[((size_t)b*6+i)*KF + t] * r;
#pragma unroll
  for (int i = 0; i < 6; ++i) {
    float v = acc[i];
#pragma unroll
    for (int o = 1; o < 64; o <<= 1) v += __shfl_xor(v, o, 64);
    acc[i] = v;
  }
  __shared__ float wred[16*6];
  const int wv = t >> 6, ln = t & 63;
  if (ln == 0)
#pragma unroll
    for (int i = 0; i < 6; ++i) wred[wv*6 + i] = acc[i];
  __syncthreads();
  __shared__ float s_g[16];
  if (t == 0) {
    float dx[6];
    for (int i = 0; i < 6; ++i) {
      float s = 0.f;
      for (int w2 = 0; w2 < 16; ++w2) s += wred[w2*6 + i];
      dx[i] = -s;
    }
    float R[9], p[3];
    se3_exp_dev(dx, R, p);
    float* g = g_buf + b*16;
    float gn[16];
    for (int r2 = 0; r2 < 3; ++r2)
      for (int c = 0; c < 4; ++c)
        gn[r2*4+c] = R[r2*3+0]*g[c] + R[r2*3+1]*g[4+c] + R[r2*3+2]*g[8+c] + p[r2]*g[12+c];
    gn[12] = 0.f; gn[13] = 0.f; gn[14] = 0.f; gn[15] = 1.f;
    for (int i = 0; i < 16; ++i) { g[i] = gn[i]; s_g[i] = gn[i]; }
    if (final_it) {
      const float* p0m = mean_tgt + b*3;
      const float* p1m = mean_src + b*3;
      float* e = est_g + b*12;
      for (int r2 = 0; r2 < 3; ++r2) {
        e[r2*4+0] = gn[r2*4+0];
        e[r2*4+1] = gn[r2*4+1];
        e[r2*4+2] = gn[r2*4+2];
        e[r2*4+3] = gn[r2*4+3]
                  - (gn[r2*4+0]*p1m[0] + gn[r2*4+1]*p1m[1] + gn[r2*4+2]*p1m[2])
                  + p0m[r2];
      }
    }
  }
  __syncthreads();
  if (!final_it) {
    if (t < 192) {
      int d = t >> 6, c = t & 63;
      W1effL[b*192 + t] = s_g[0*4+d]*W1[c] + s_g[1*4+d]*W1[64+c] + s_g[2*4+d]*W1[128+c];
    } else if (t < 256) {
      int i = t - 192;
      b1effL[b*64 + i] = b1[i] + s_g[3]*W1[i] + s_g[7]*W1[64+i] + s_g[11]*W1[128+i];
    }
  }
}

__global__ void loss_kernel(const float* __restrict__ p_src, const float* __restrict__ est_g,
                            const float* __restrict__ igt_inv, float* __restrict__ loss_out) {
  int b = blockIdx.y, tile = blockIdx.x, t = threadIdx.x;
  int n = tile*256 + t;
  const float* e = est_g + b*12;
  const float* v = igt_inv + b*12;
  const float* p = p_src + ((size_t)b*NPTS + n)*3;
  float px = p[0], py = p[1], pz = p[2];
  float s = 0.f;
#pragma unroll
  for (int r2 = 0; r2 < 3; ++r2) {
    float d1 = e[r2*4+0]*px + e[r2*4+1]*py + e[r2*4+2]*pz + e[r2*4+3];
    float d2 = v[r2*4+0]*px + v[r2*4+1]*py + v[r2*4+2]*pz + v[r2*4+3];
    s += fabsf(d1 - d2);
  }
  __shared__ float red[256];
  red[t] = s;
  __syncthreads();
  for (int st = 128; st > 0; st >>= 1) {
    if (t < st) red[t] += red[t+st];
    __syncthreads();
  }
  if (t == 0) atomicAdd(loss_out, red[0] * (1.f/((float)BATCH*NPTS*3)));
}

// ---------------- launcher ----------------
extern "C" void kernel_launch(void* const* d_in, const int* in_sizes, int n_in,
                              void* d_out, int out_size, void* d_ws, size_t ws_size,
                              hipStream_t stream) {
  const float* p_src     = (const float*)d_in[0];
  const float* p_tgt     = (const float*)d_in[1];
  const float* igt_twist = (const float*)d_in[2];
  const float* dt        = (const float*)d_in[3];
  const float* W1        = (const float*)d_in[4];
  const float* b1        = (const float*)d_in[5];
  const float* W2        = (const float*)d_in[6];
  const float* b2        = (const float*)d_in[7];
  const float* W3        = (const float*)d_in[8];
  float* out = (float*)d_out;

  float* ws = (float*)d_ws;
  float* mean_tgt = ws;  ws += 32;
  float* mean_src = ws;  ws += 32;
  float* W1eff7   = ws;  ws += 7*192;
  float* b1eff7   = ws;  ws += 7*64;
  float* feats0   = ws;  ws += BATCH*KF;
  float* W1effL   = ws;  ws += BATCH*192;
  float* b1effL   = ws;  ws += BATCH*64;
  float* g_buf    = ws;  ws += BATCH*16;
  float* pinvb    = ws;  ws += BATCH*6*KF;
  float* igt_inv  = ws;  ws += 96;
  float* est_g    = ws;  ws += 96;
  _Float16* W2h = (_Float16*)ws;  ws += 8192/2;
  _Float16* W2l = (_Float16*)ws;  ws += 8192/2;
  _Float16* W3p = (_Float16*)ws;  ws += 262144/2;   // 64 tiles x 8 KB
  float* partialB = ws;  ws += 56*8*KF;             // big-encode partials (1.75 MB)
  float* partial2 = ws;  ws += BATCH*32*KF;         // loop-encode partials (1 MB)

  float* r_out    = out;
  float* loss_out = out + BATCH*KF;

  means_kernel<<<dim3(BATCH*2), 256, 0, stream>>>(p_tgt, p_src, mean_tgt, mean_src);
  setup_kernel<<<1, 256, 0, stream>>>(dt, W1, b1, igt_twist, W1eff7, b1eff7,
                                      W1effL, b1effL, g_buf, igt_inv, loss_out);
  pack_w2_kernel<<<dim3(8192/256), 256, 0, stream>>>(W2, W2h, W2l);
  pack_w3_kernel<<<dim3(131072/256), 256, 0, stream>>>(W3, W3p);

  encode_big<<<dim3(8, 7, BATCH), 256, 0, stream>>>(
      p_tgt, mean_tgt, W1eff7, b1eff7, W2h, W2l, W3p, b2, partialB);
  pinv_kernel<<<dim3(BATCH), 1024, 0, stream>>>(partialB, dt, pinvb, feats0);

  for (int it = 0; it < 5; ++it) {
    encode_loop<<<dim3(32, 4, BATCH), 256, 0, stream>>>(
        p_src, mean_src, W1effL, b1effL, W2h, W2l, W3p, b2, partial2);
    update_kernel<<<dim3(BATCH), 1024, 0, stream>>>(
        feats0, partial2, pinvb, g_buf, W1, b1, W1effL, b1effL, r_out,
        mean_tgt, mean_src, est_g, (it == 4) ? 1 : 0);
  }
  loss_kernel<<<dim3(NPTS/256, BATCH), 256, 0, stream>>>(p_src, est_g, igt_inv, loss_out);
}

// Round 11
// 302.335 us; speedup vs baseline: 2.4741x; 1.0408x over previous
//
#include <hip/hip_runtime.h>
#include <math.h>

#define BATCH 8
#define NPTS 2048
#define KF 1024

typedef _Float16 f16x8 __attribute__((ext_vector_type(8)));
typedef float f32x4 __attribute__((ext_vector_type(4)));

// 16x16x32 layouts HW-verified (m89/m91/m97/m120):
//  A: lane holds A[m=lane&15][k=(lane>>4)*8+j]
//  B: lane holds B[k=(lane>>4)*8+j][n=lane&15]
//  C/D: lane,reg holds C[row=(lane>>4)*4+reg][col=lane&15]
#define MFMA16(a,b,c) __builtin_amdgcn_mfma_f32_16x16x32_f16((a),(b),(c),0,0,0)

#define FSCALE 256.0f
#define INV16  (1.0f/65536.0f)

// fp16 2-way split of (x*256); 3 products (hh, hl, lh), ll dropped (~4e-4 on r).
__device__ __forceinline__ void split_f16s(float x, _Float16& hi, _Float16& lo) {
  float xs = x * FSCALE;
  hi = (_Float16)xs;
  lo = (_Float16)(xs - (float)hi);
}

// ---------------- misc device helpers ----------------
__device__ __forceinline__ void mat3mul(const float* A, const float* Bm, float* C) {
#pragma unroll
  for (int i = 0; i < 3; ++i)
#pragma unroll
    for (int j = 0; j < 3; ++j)
      C[i*3+j] = A[i*3+0]*Bm[0*3+j] + A[i*3+1]*Bm[1*3+j] + A[i*3+2]*Bm[2*3+j];
}

__device__ void se3_exp_dev(const float* x, float* R, float* p) {
  float wx = x[0], wy = x[1], wz = x[2];
  float vx = x[3], vy = x[4], vz = x[5];
  float t2 = wx*wx + wy*wy + wz*wz;
  float t = sqrtf(t2);
  float A, Bc, Cc;
  if (t < 1e-6f) {
    A  = 1.f - t2*(1.f/6.f);
    Bc = 0.5f - t2*(1.f/24.f);
    Cc = (1.f/6.f) - t2*(1.f/120.f);
  } else {
    float s = sinf(t), c = cosf(t);
    A  = s / t;
    Bc = (1.f - c) / t2;
    Cc = (t - s) / (t2 * t);
  }
  float W[9]  = {0.f, -wz, wy,  wz, 0.f, -wx,  -wy, wx, 0.f};
  float W2[9];
  mat3mul(W, W, W2);
#pragma unroll
  for (int i = 0; i < 9; ++i) {
    float I = (i == 0 || i == 4 || i == 8) ? 1.f : 0.f;
    R[i] = I + A*W[i] + Bc*W2[i];
  }
  float V[9];
#pragma unroll
  for (int i = 0; i < 9; ++i) {
    float I = (i == 0 || i == 4 || i == 8) ? 1.f : 0.f;
    V[i] = I + Bc*W[i] + Cc*W2[i];
  }
  p[0] = V[0]*vx + V[1]*vy + V[2]*vz;
  p[1] = V[3]*vx + V[4]*vy + V[5]*vz;
  p[2] = V[6]*vx + V[7]*vy + V[8]*vz;
}

// ---------------- small kernels (verified) ----------------
__global__ void means_kernel(const float* __restrict__ tgt, const float* __restrict__ src,
                             float* __restrict__ mean_tgt, float* __restrict__ mean_src) {
  int which = blockIdx.x & 1, b = blockIdx.x >> 1;
  const float* p = (which ? src : tgt) + (size_t)b*NPTS*3;
  float* m = (which ? mean_src : mean_tgt) + b*3;
  int t = threadIdx.x;
  float s0 = 0.f, s1 = 0.f, s2 = 0.f;
  for (int i = t; i < NPTS; i += 256) {
    s0 += p[i*3+0]; s1 += p[i*3+1]; s2 += p[i*3+2];
  }
  __shared__ float red[256][3];
  red[t][0] = s0; red[t][1] = s1; red[t][2] = s2;
  __syncthreads();
  for (int s = 128; s > 0; s >>= 1) {
    if (t < s) { red[t][0] += red[t+s][0]; red[t][1] += red[t+s][1]; red[t][2] += red[t+s][2]; }
    __syncthreads();
  }
  if (t == 0) {
    m[0] = red[0][0] * (1.f/NPTS);
    m[1] = red[0][1] * (1.f/NPTS);
    m[2] = red[0][2] * (1.f/NPTS);
  }
}

__global__ void setup_kernel(const float* __restrict__ dt, const float* __restrict__ W1,
                             const float* __restrict__ b1, const float* __restrict__ igt_twist,
                             float* __restrict__ W1eff7, float* __restrict__ b1eff7,
                             float* __restrict__ W1effL, float* __restrict__ b1effL,
                             float* __restrict__ g_buf, float* __restrict__ igt_inv,
                             float* __restrict__ loss_out) {
  int t = threadIdx.x;
  for (int i = t; i < BATCH*192;  i += 256) W1effL[i] = W1[i % 192];
  for (int i = t; i < BATCH*64;   i += 256) b1effL[i] = b1[i & 63];
  if (t < 192) W1eff7[t] = W1[t];
  if (t < 64)  b1eff7[t] = b1[t];
  if (t < BATCH*16) {
    int i = t & 15;
    g_buf[t] = (i == 0 || i == 5 || i == 10 || i == 15) ? 1.f : 0.f;
  }
  if (t == 0) *loss_out = 0.f;
  if (t < 6) {
    float tw[6] = {0.f,0.f,0.f,0.f,0.f,0.f};
    tw[t] = -dt[t];
    float R[9], tr[3];
    se3_exp_dev(tw, R, tr);
    float* Wd = W1eff7 + (t+1)*192;
    for (int d = 0; d < 3; ++d)
      for (int c = 0; c < 64; ++c)
        Wd[d*64+c] = R[0*3+d]*W1[c] + R[1*3+d]*W1[64+c] + R[2*3+d]*W1[128+c];
    float* bd = b1eff7 + (t+1)*64;
    for (int c = 0; c < 64; ++c)
      bd[c] = b1[c] + tr[0]*W1[c] + tr[1]*W1[64+c] + tr[2]*W1[128+c];
  }
  if (t >= 32 && t < 32+BATCH) {
    int b = t - 32;
    float R[9], tr[3];
    se3_exp_dev(igt_twist + b*6, R, tr);
    float* inv = igt_inv + b*12;
    for (int r = 0; r < 3; ++r) {
      inv[r*4+0] = R[0*3+r];
      inv[r*4+1] = R[1*3+r];
      inv[r*4+2] = R[2*3+r];
      inv[r*4+3] = -(R[0*3+r]*tr[0] + R[1*3+r]*tr[1] + R[2*3+r]*tr[2]);
    }
  }
}

// ---------------- weight packs (verified layouts) ----------------
// W3p: [nt][lev][ks3][lane][8], 4096 f16 (8 KB) per nt tile, linear.
__global__ void pack_w3_kernel(const float* __restrict__ W3, _Float16* __restrict__ P) {
  int i = blockIdx.x*256 + threadIdx.x;   // 128*1024
  int k = i >> 10, n = i & 1023;
  _Float16 hi, lo;
  split_f16s(W3[i], hi, lo);
  int nt = n >> 4, col = n & 15;
  int ks3 = k >> 5, rr = k & 31;
  int lane = (rr >> 3)*16 + col, jj = rr & 7;
  size_t base = (size_t)nt*4096;
  P[base + ((0*4 + ks3)*64 + lane)*8 + jj] = hi;
  P[base + ((1*4 + ks3)*64 + lane)*8 + jj] = lo;
}

__global__ void pack_w2_kernel(const float* __restrict__ W2,
                               _Float16* __restrict__ H, _Float16* __restrict__ L) {
  int i = blockIdx.x*256 + threadIdx.x;   // 64*128
  int k = i >> 7, n = i & 127;
  _Float16 hi, lo;
  split_f16s(W2[i], hi, lo);
  int nt2 = n >> 4, col = n & 15;
  int ks = k >> 5, rr = k & 31;
  int lane = (rr >> 3)*16 + col, jj = rr & 7;
  int dst = ((nt2*2 + ks)*64 + lane)*8 + jj;
  H[dst] = hi; L[dst] = lo;
}

// ---------------- shared encode pieces ----------------
__device__ __forceinline__ f32x4 zero4() {
  f32x4 z; z[0]=0.f; z[1]=0.f; z[2]=0.f; z[3]=0.f; return z;
}

// layer1 + layer2 (3-product) for one ptile -> layer-3 A fragments, via
// per-wave LDS relayout scratch. b3 dropped everywhere (cancels in J and r).
__device__ __forceinline__ void l12_ptile(
    float px, float py, float pz,
    const float* __restrict__ w1, const float* __restrict__ bb1,
    const _Float16* __restrict__ W2h, const _Float16* __restrict__ W2l,
    const float* __restrict__ b2,
    _Float16* scr, int l, int lm, int q,
    f16x8 (&A3h)[4], f16x8 (&A3l)[4]) {
  f16x8 A2h[2], A2l[2];
#pragma unroll
  for (int ks = 0; ks < 2; ++ks) {
    const int c0 = ks*32 + q*8;
    float wa[8], wb[8], wc[8], bv[8];
    *(float4*)&wa[0] = *(const float4*)(w1 + c0);
    *(float4*)&wa[4] = *(const float4*)(w1 + c0 + 4);
    *(float4*)&wb[0] = *(const float4*)(w1 + 64 + c0);
    *(float4*)&wb[4] = *(const float4*)(w1 + 64 + c0 + 4);
    *(float4*)&wc[0] = *(const float4*)(w1 + 128 + c0);
    *(float4*)&wc[4] = *(const float4*)(w1 + 128 + c0 + 4);
    *(float4*)&bv[0] = *(const float4*)(bb1 + c0);
    *(float4*)&bv[4] = *(const float4*)(bb1 + c0 + 4);
#pragma unroll
    for (int jj = 0; jj < 8; ++jj) {
      float h = fmaf(px, wa[jj], fmaf(py, wb[jj], fmaf(pz, wc[jj], bv[jj])));
      h = fmaxf(h, 0.f);
      _Float16 hi, lo;
      split_f16s(h, hi, lo);
      A2h[ks][jj] = hi; A2l[ks][jj] = lo;
    }
  }
#pragma unroll
  for (int nt2 = 0; nt2 < 8; ++nt2) {
    f32x4 acc = zero4();
#pragma unroll
    for (int ks = 0; ks < 2; ++ks) {
      const int base = ((nt2*2 + ks)*64 + l)*8;
      const f16x8 Bh = *(const f16x8*)(W2h + base);
      const f16x8 Bl = *(const f16x8*)(W2l + base);
      acc = MFMA16(A2l[ks], Bh, acc);
      acc = MFMA16(A2h[ks], Bl, acc);
      acc = MFMA16(A2h[ks], Bh, acc);
    }
    const int c2 = nt2*16 + lm;
    const float b2v = b2[c2];
    const int ks3 = c2 >> 5;
    const int k31 = c2 & 31;
    const int qw = k31 >> 3, jw = k31 & 7;
#pragma unroll
    for (int r = 0; r < 4; ++r) {
      const int mrow = q*4 + r;
      float h = fmaxf(acc[r]*INV16 + b2v, 0.f);
      _Float16 hi, lo;
      split_f16s(h, hi, lo);
      const int idx = (ks3*64 + qw*16 + mrow)*8 + jw;
      scr[idx] = hi;
      scr[2048 + idx] = lo;
    }
  }
#pragma unroll
  for (int ks3 = 0; ks3 < 4; ++ks3) {
    const int base = (ks3*64 + l)*8;
    A3h[ks3] = *(const f16x8*)&scr[base];
    A3l[ks3] = *(const f16x8*)&scr[2048 + base];
  }
}

// ---------------- BIG encode: 4 ptiles/wave, LDS B dbuf, in-block cross-wave
// max -> 8 partial slots (one per pblk). grid (8,7,8) x 256. ----------------
__global__ __launch_bounds__(256, 2) void encode_big(
    const float* __restrict__ pts, const float* __restrict__ mean,
    const float* __restrict__ W1e, const float* __restrict__ b1e,
    const _Float16* __restrict__ W2h, const _Float16* __restrict__ W2l,
    const _Float16* __restrict__ W3p, const float* __restrict__ b2,
    float* __restrict__ partial) {
  const int t = threadIdx.x;
  const int w = t >> 6, l = t & 63;
  const int lm = l & 15, q = l >> 4;
  const int pblk = blockIdx.x;
  const int j = blockIdx.y;
  const int b = blockIdx.z;

  __shared__ __align__(16) _Float16 smem[16384];   // 32 KB

  const int ptbase = pblk*256 + w*64;
  float mx0 = mean[b*3+0], my0 = mean[b*3+1], mz0 = mean[b*3+2];
  const float* w1 = W1e + j*192;
  const float* bb1 = b1e + j*64;

  f16x8 A3h[4][4], A3l[4][4];
  _Float16* scr = smem + w*4096;
#pragma unroll
  for (int p = 0; p < 4; ++p) {
    const float* pp = pts + ((size_t)b*NPTS + ptbase + p*16 + lm)*3;
    l12_ptile(pp[0]-mx0, pp[1]-my0, pp[2]-mz0, w1, bb1, W2h, W2l, b2,
              scr, l, lm, q, A3h[p], A3l[p]);
  }
  __syncthreads();   // scr done; smem: [0,16KB) B dbuf, [16KB,32KB) maxbuf

  float* maxb = (float*)(smem + 8192);   // float[4][1024]
  {
    f16x8 s0 = *(const f16x8*)(W3p + t*8);
    f16x8 s1 = *(const f16x8*)(W3p + 2048 + t*8);
    *(f16x8*)&smem[t*8] = s0;
    *(f16x8*)&smem[2048 + t*8] = s1;
  }
  __syncthreads();

  for (int k = 0; k < 64; ++k) {
    const int cur = (k & 1)*4096;
    const int nxt = cur ^ 4096;
    f16x8 s0, s1;
    const int have_next = (k + 1 < 64);
    if (have_next) {
      const _Float16* src = W3p + (size_t)(k+1)*4096;
      s0 = *(const f16x8*)(src + t*8);
      s1 = *(const f16x8*)(src + 2048 + t*8);
    }
    f16x8 B[2][4];
#pragma unroll
    for (int lev = 0; lev < 2; ++lev)
#pragma unroll
      for (int ks = 0; ks < 4; ++ks)
        B[lev][ks] = *(const f16x8*)&smem[cur + ((lev*4 + ks)*64 + l)*8];

    f32x4 a[4] = {zero4(), zero4(), zero4(), zero4()};
#pragma unroll
    for (int ks = 0; ks < 4; ++ks) {
#pragma unroll
      for (int p = 0; p < 4; ++p) a[p] = MFMA16(A3l[p][ks], B[0][ks], a[p]);  // l*h
#pragma unroll
      for (int p = 0; p < 4; ++p) a[p] = MFMA16(A3h[p][ks], B[1][ks], a[p]);  // h*l
#pragma unroll
      for (int p = 0; p < 4; ++p) a[p] = MFMA16(A3h[p][ks], B[0][ks], a[p]);  // h*h
    }
    float mx = -INFINITY;
#pragma unroll
    for (int p = 0; p < 4; ++p)
#pragma unroll
      for (int r = 0; r < 4; ++r) mx = fmaxf(mx, a[p][r]);
    mx = fmaxf(mx, __shfl_xor(mx, 16, 64));
    mx = fmaxf(mx, __shfl_xor(mx, 32, 64));
    if (l < 16) maxb[w*1024 + k*16 + lm] = mx;

    if (have_next) {
      *(f16x8*)&smem[nxt + t*8] = s0;
      *(f16x8*)&smem[nxt + 2048 + t*8] = s1;
    }
    __syncthreads();
  }
  // cross-wave max -> one partial slot per block
  float* pout = partial + ((size_t)(j*BATCH + b)*8 + pblk)*KF;
  for (int f = t; f < KF; f += 256) {
    float m = fmaxf(fmaxf(maxb[f], maxb[1024+f]), fmaxf(maxb[2048+f], maxb[3072+f]));
    pout[f] = m*INV16;
  }
}

// ---------------- pinv: grid(8) x 512 thr (2 k/thread, 8 waves).
// Fuses the 8-slot partial reduce, H build, and pinv write. The 6x6 inverse is
// a fully-unrolled register-resident f64 Cholesky (H=J^T J is SPD, no pivoting;
// static indices after unroll -> no scratch. R10's pivoted GE ran from scratch
// memory: 95 us at ~0% VALUBusy). Emits f0 for update. ----------------
__global__ __launch_bounds__(512) void pinv_kernel(
    const float* __restrict__ partialB, const float* __restrict__ dt,
    float* __restrict__ pinvb, float* __restrict__ feats0) {
  const int b = blockIdx.x, t = threadIdx.x;
  float Jk2[2][6];
  float H[21];
#pragma unroll
  for (int i = 0; i < 21; ++i) H[i] = 0.f;
#pragma unroll
  for (int h = 0; h < 2; ++h) {
    const int kf = t + h*512;
    float fv[7];
#pragma unroll
    for (int j = 0; j < 7; ++j) {
      const float* ps = partialB + ((size_t)(j*BATCH + b)*8)*KF + kf;
      float m = ps[0];
#pragma unroll
      for (int s = 1; s < 8; ++s) m = fmaxf(m, ps[(size_t)s*KF]);
      fv[j] = m;
    }
    feats0[(size_t)b*KF + kf] = fv[0];
#pragma unroll
    for (int i = 0; i < 6; ++i) Jk2[h][i] = (fv[0] - fv[1+i]) / dt[i];
    int idx = 0;
#pragma unroll
    for (int i = 0; i < 6; ++i)
#pragma unroll
      for (int jj = i; jj < 6; ++jj) H[idx++] += Jk2[h][i]*Jk2[h][jj];
  }
#pragma unroll
  for (int i = 0; i < 21; ++i) {
    float v = H[i];
#pragma unroll
    for (int o = 1; o < 64; o <<= 1) v += __shfl_xor(v, o, 64);
    H[i] = v;
  }
  __shared__ float hred[8*21];
  __shared__ float s_hinv[36];
  const int wv = t >> 6, ln = t & 63;
  if (ln == 0)
#pragma unroll
    for (int i = 0; i < 21; ++i) hred[wv*21 + i] = H[i];
  __syncthreads();
  if (t == 0) {
    float Ht[21];
#pragma unroll
    for (int i = 0; i < 21; ++i) {
      float s = 0.f;
#pragma unroll
      for (int w2 = 0; w2 < 8; ++w2) s += hred[w2*21 + i];
      Ht[i] = s;
    }
    // unpack upper-packed H into lower-triangular L (L[i][j], j<=i)
    double L[6][6];
#pragma unroll
    for (int i = 0; i < 6; ++i)
#pragma unroll
      for (int j = 0; j <= i; ++j)
        L[i][j] = (double)Ht[j*6 - j*(j-1)/2 + (i - j)];
    // Cholesky: L <- chol(H), fully unrolled, registers only
#pragma unroll
    for (int k = 0; k < 6; ++k) {
      double s = L[k][k];
#pragma unroll
      for (int m2 = 0; m2 < k; ++m2) s -= L[k][m2]*L[k][m2];
      double d = sqrt(s);
      double di = 1.0/d;
      L[k][k] = d;
#pragma unroll
      for (int i2 = k+1; i2 < 6; ++i2) {
        double s2 = L[i2][k];
#pragma unroll
        for (int m2 = 0; m2 < k; ++m2) s2 -= L[i2][m2]*L[k][m2];
        L[i2][k] = s2*di;
      }
    }
    // invert L in place (lower-triangular inverse)
#pragma unroll
    for (int i2 = 0; i2 < 6; ++i2) {
      double dii = 1.0/L[i2][i2];
#pragma unroll
      for (int j2 = 0; j2 < i2; ++j2) {
        double s = 0.0;
#pragma unroll
        for (int k2 = j2; k2 < i2; ++k2) s += L[i2][k2]*L[k2][j2];
        L[i2][j2] = -dii*s;
      }
      L[i2][i2] = dii;
    }
    // Hinv = Linv^T * Linv
#pragma unroll
    for (int i2 = 0; i2 < 6; ++i2)
#pragma unroll
      for (int j2 = 0; j2 <= i2; ++j2) {
        double s = 0.0;
#pragma unroll
        for (int k2 = i2; k2 < 6; ++k2) s += L[k2][i2]*L[k2][j2];
        s_hinv[i2*6+j2] = (float)s;
        s_hinv[j2*6+i2] = (float)s;
      }
  }
  __syncthreads();
#pragma unroll
  for (int h = 0; h < 2; ++h) {
    const int kf = t + h*512;
#pragma unroll
    for (int i = 0; i < 6; ++i) {
      float s = 0.f;
#pragma unroll
      for (int jj = 0; jj < 6; ++jj) s += s_hinv[i*6+jj] * Jk2[h][jj];
      pinvb[((size_t)b*6 + i)*KF + kf] = s;
    }
  }
}

// ---------------- LOOP encode: fused l1-l3, cross-wave max -> 32 slots ----------------
// grid (32, 4, 8) x 256; block writes its 256-feature stripe of slot pblk.
__global__ __launch_bounds__(256, 3) void encode_loop(
    const float* __restrict__ pts, const float* __restrict__ mean,
    const float* __restrict__ W1e, const float* __restrict__ b1e,
    const _Float16* __restrict__ W2h, const _Float16* __restrict__ W2l,
    const _Float16* __restrict__ W3p, const float* __restrict__ b2,
    float* __restrict__ partial2) {
  const int t = threadIdx.x;
  const int w = t >> 6, l = t & 63;
  const int lm = l & 15, q = l >> 4;
  const int pblk = blockIdx.x;
  const int fg = blockIdx.y;
  const int b = blockIdx.z;
  const int nt0 = fg*16;

  __shared__ __align__(16) _Float16 smem[16384];

  const int pt = pblk*64 + w*16;
  float mx0 = mean[b*3+0], my0 = mean[b*3+1], mz0 = mean[b*3+2];
  const float* w1 = W1e + b*192;
  const float* bb1 = b1e + b*64;

  f16x8 A3h[4], A3l[4];
  {
    const float* pp = pts + ((size_t)b*NPTS + pt + lm)*3;
    l12_ptile(pp[0]-mx0, pp[1]-my0, pp[2]-mz0, w1, bb1, W2h, W2l, b2,
              smem + w*4096, l, lm, q, A3h, A3l);
  }
  __syncthreads();

  float* maxb = (float*)(smem + 8192);   // float[4][256]
  {
    const _Float16* src = W3p + (size_t)nt0*4096;
    f16x8 s0 = *(const f16x8*)(src + t*8);
    f16x8 s1 = *(const f16x8*)(src + 2048 + t*8);
    *(f16x8*)&smem[t*8] = s0;
    *(f16x8*)&smem[2048 + t*8] = s1;
  }
  __syncthreads();

  for (int k = 0; k < 16; ++k) {
    const int cur = (k & 1)*4096;
    const int nxt = cur ^ 4096;
    f16x8 s0, s1;
    const int have_next = (k + 1 < 16);
    if (have_next) {
      const _Float16* src = W3p + (size_t)(nt0 + k + 1)*4096;
      s0 = *(const f16x8*)(src + t*8);
      s1 = *(const f16x8*)(src + 2048 + t*8);
    }
    f16x8 B[2][4];
#pragma unroll
    for (int lev = 0; lev < 2; ++lev)
#pragma unroll
      for (int ks = 0; ks < 4; ++ks)
        B[lev][ks] = *(const f16x8*)&smem[cur + ((lev*4 + ks)*64 + l)*8];

    f32x4 a = zero4();
#pragma unroll
    for (int ks = 0; ks < 4; ++ks) {
      a = MFMA16(A3l[ks], B[0][ks], a);
      a = MFMA16(A3h[ks], B[1][ks], a);
      a = MFMA16(A3h[ks], B[0][ks], a);
    }
    float mx = fmaxf(fmaxf(a[0], a[1]), fmaxf(a[2], a[3]));
    mx = fmaxf(mx, __shfl_xor(mx, 16, 64));
    mx = fmaxf(mx, __shfl_xor(mx, 32, 64));
    if (l < 16) maxb[w*256 + k*16 + lm] = mx;

    if (have_next) {
      *(f16x8*)&smem[nxt + t*8] = s0;
      *(f16x8*)&smem[nxt + 2048 + t*8] = s1;
    }
    __syncthreads();
  }
  if (t < 256) {
    float m = fmaxf(fmaxf(maxb[t], maxb[256+t]), fmaxf(maxb[512+t], maxb[768+t]));
    partial2[((size_t)b*32 + pblk)*KF + fg*256 + t] = m*INV16;
  }
}

// ---------------- update: grid(8) x 1024 thr (1 feature/thread, 16 waves).
// 32-slot max -> f1, r, shfl-reduced 6-dot, thread-0 GN step. ----------------
__global__ __launch_bounds__(1024) void update_kernel(
    const float* __restrict__ feats0, const float* __restrict__ partial2,
    const float* __restrict__ pinv, float* __restrict__ g_buf,
    const float* __restrict__ W1, const float* __restrict__ b1,
    float* __restrict__ W1effL, float* __restrict__ b1effL,
    float* __restrict__ r_out,
    const float* __restrict__ mean_tgt, const float* __restrict__ mean_src,
    float* __restrict__ est_g, int final_it) {
  const int b = blockIdx.x, t = threadIdx.x;
  const float* ps = partial2 + (size_t)b*32*KF + t;
  float m = ps[0];
#pragma unroll
  for (int s = 1; s < 32; ++s) m = fmaxf(m, ps[(size_t)s*KF]);
  float r = m - feats0[(size_t)b*KF + t];
  r_out[(size_t)b*KF + t] = r;
  float acc[6];
#pragma unroll
  for (int i = 0; i < 6; ++i) acc[i] = pinv[((size_t)b*6+i)*KF + t] * r;
#pragma unroll
  for (int i = 0; i < 6; ++i) {
    float v = acc[i];
#pragma unroll
    for (int o = 1; o < 64; o <<= 1) v += __shfl_xor(v, o, 64);
    acc[i] = v;
  }
  __shared__ float wred[16*6];
  const int wv = t >> 6, ln = t & 63;
  if (ln == 0)
#pragma unroll
    for (int i = 0; i < 6; ++i) wred[wv*6 + i] = acc[i];
  __syncthreads();
  __shared__ float s_g[16];
  if (t == 0) {
    float dx[6];
    for (int i = 0; i < 6; ++i) {
      float s = 0.f;
      for (int w2 = 0; w2 < 16; ++w2) s += wred[w2*6 + i];
      dx[i] = -s;
    }
    float R[9], p[3];
    se3_exp_dev(dx, R, p);
    float* g = g_buf + b*16;
    float gn[16];
    for (int r2 = 0; r2 < 3; ++r2)
      for (int c = 0; c < 4; ++c)
        gn[r2*4+c] = R[r2*3+0]*g[c] + R[r2*3+1]*g[4+c] + R[r2*3+2]*g[8+c] + p[r2]*g[12+c];
    gn[12] = 0.f; gn[13] = 0.f; gn[14] = 0.f; gn[15] = 1.f;
    for (int i = 0; i < 16; ++i) { g[i] = gn[i]; s_g[i] = gn[i]; }
    if (final_it) {
      const float* p0m = mean_tgt + b*3;
      const float* p1m = mean_src + b*3;
      float* e = est_g + b*12;
      for (int r2 = 0; r2 < 3; ++r2) {
        e[r2*4+0] = gn[r2*4+0];
        e[r2*4+1] = gn[r2*4+1];
        e[r2*4+2] = gn[r2*4+2];
        e[r2*4+3] = gn[r2*4+3]
                  - (gn[r2*4+0]*p1m[0] + gn[r2*4+1]*p1m[1] + gn[r2*4+2]*p1m[2])
                  + p0m[r2];
      }
    }
  }
  __syncthreads();
  if (!final_it) {
    if (t < 192) {
      int d = t >> 6, c = t & 63;
      W1effL[b*192 + t] = s_g[0*4+d]*W1[c] + s_g[1*4+d]*W1[64+c] + s_g[2*4+d]*W1[128+c];
    } else if (t < 256) {
      int i = t - 192;
      b1effL[b*64 + i] = b1[i] + s_g[3]*W1[i] + s_g[7]*W1[64+i] + s_g[11]*W1[128+i];
    }
  }
}

__global__ void loss_kernel(const float* __restrict__ p_src, const float* __restrict__ est_g,
                            const float* __restrict__ igt_inv, float* __restrict__ loss_out) {
  int b = blockIdx.y, tile = blockIdx.x, t = threadIdx.x;
  int n = tile*256 + t;
  const float* e = est_g + b*12;
  const float* v = igt_inv + b*12;
  const float* p = p_src + ((size_t)b*NPTS + n)*3;
  float px = p[0], py = p[1], pz = p[2];
  float s = 0.f;
#pragma unroll
  for (int r2 = 0; r2 < 3; ++r2) {
    float d1 = e[r2*4+0]*px + e[r2*4+1]*py + e[r2*4+2]*pz + e[r2*4+3];
    float d2 = v[r2*4+0]*px + v[r2*4+1]*py + v[r2*4+2]*pz + v[r2*4+3];
    s += fabsf(d1 - d2);
  }
  __shared__ float red[256];
  red[t] = s;
  __syncthreads();
  for (int st = 128; st > 0; st >>= 1) {
    if (t < st) red[t] += red[t+st];
    __syncthreads();
  }
  if (t == 0) atomicAdd(loss_out, red[0] * (1.f/((float)BATCH*NPTS*3)));
}

// ---------------- launcher ----------------
extern "C" void kernel_launch(void* const* d_in, const int* in_sizes, int n_in,
                              void* d_out, int out_size, void* d_ws, size_t ws_size,
                              hipStream_t stream) {
  const float* p_src     = (const float*)d_in[0];
  const float* p_tgt     = (const float*)d_in[1];
  const float* igt_twist = (const float*)d_in[2];
  const float* dt        = (const float*)d_in[3];
  const float* W1        = (const float*)d_in[4];
  const float* b1        = (const float*)d_in[5];
  const float* W2        = (const float*)d_in[6];
  const float* b2        = (const float*)d_in[7];
  const float* W3        = (const float*)d_in[8];
  float* out = (float*)d_out;

  float* ws = (float*)d_ws;
  float* mean_tgt = ws;  ws += 32;
  float* mean_src = ws;  ws += 32;
  float* W1eff7   = ws;  ws += 7*192;
  float* b1eff7   = ws;  ws += 7*64;
  float* feats0   = ws;  ws += BATCH*KF;
  float* W1effL   = ws;  ws += BATCH*192;
  float* b1effL   = ws;  ws += BATCH*64;
  float* g_buf    = ws;  ws += BATCH*16;
  float* pinvb    = ws;  ws += BATCH*6*KF;
  float* igt_inv  = ws;  ws += 96;
  float* est_g    = ws;  ws += 96;
  _Float16* W2h = (_Float16*)ws;  ws += 8192/2;
  _Float16* W2l = (_Float16*)ws;  ws += 8192/2;
  _Float16* W3p = (_Float16*)ws;  ws += 262144/2;   // 64 tiles x 8 KB
  float* partialB = ws;  ws += 56*8*KF;             // big-encode partials (1.75 MB)
  float* partial2 = ws;  ws += BATCH*32*KF;         // loop-encode partials (1 MB)

  float* r_out    = out;
  float* loss_out = out + BATCH*KF;

  means_kernel<<<dim3(BATCH*2), 256, 0, stream>>>(p_tgt, p_src, mean_tgt, mean_src);
  setup_kernel<<<1, 256, 0, stream>>>(dt, W1, b1, igt_twist, W1eff7, b1eff7,
                                      W1effL, b1effL, g_buf, igt_inv, loss_out);
  pack_w2_kernel<<<dim3(8192/256), 256, 0, stream>>>(W2, W2h, W2l);
  pack_w3_kernel<<<dim3(131072/256), 256, 0, stream>>>(W3, W3p);

  encode_big<<<dim3(8, 7, BATCH), 256, 0, stream>>>(
      p_tgt, mean_tgt, W1eff7, b1eff7, W2h, W2l, W3p, b2, partialB);
  pinv_kernel<<<dim3(BATCH), 512, 0, stream>>>(partialB, dt, pinvb, feats0);

  for (int it = 0; it < 5; ++it) {
    encode_loop<<<dim3(32, 4, BATCH), 256, 0, stream>>>(
        p_src, mean_src, W1effL, b1effL, W2h, W2l, W3p, b2, partial2);
    update_kernel<<<dim3(BATCH), 1024, 0, stream>>>(
        feats0, partial2, pinvb, g_buf, W1, b1, W1effL, b1effL, r_out,
        mean_tgt, mean_src, est_g, (it == 4) ? 1 : 0);
  }
  loss_kernel<<<dim3(NPTS/256, BATCH), 256, 0, stream>>>(p_src, est_g, igt_inv, loss_out);
}

// Round 12
// 290.803 us; speedup vs baseline: 2.5722x; 1.0397x over previous
//
#include <hip/hip_runtime.h>
#include <math.h>

#define BATCH 8
#define NPTS 2048
#define KF 1024

typedef _Float16 f16x8 __attribute__((ext_vector_type(8)));
typedef float f32x4 __attribute__((ext_vector_type(4)));

// 16x16x32 layouts HW-verified (m89/m91/m97/m120):
//  A: lane holds A[m=lane&15][k=(lane>>4)*8+j]
//  B: lane holds B[k=(lane>>4)*8+j][n=lane&15]
//  C/D: lane,reg holds C[row=(lane>>4)*4+reg][col=lane&15]
#define MFMA16(a,b,c) __builtin_amdgcn_mfma_f32_16x16x32_f16((a),(b),(c),0,0,0)

#define FSCALE 256.0f
#define INV16  (1.0f/65536.0f)

// fp16 2-way split of (x*256); 3 products (hh, hl, lh), ll dropped (~4e-4 on r).
__device__ __forceinline__ void split_f16s(float x, _Float16& hi, _Float16& lo) {
  float xs = x * FSCALE;
  hi = (_Float16)xs;
  lo = (_Float16)(xs - (float)hi);
}

// ---------------- misc device helpers ----------------
__device__ __forceinline__ void mat3mul(const float* A, const float* Bm, float* C) {
#pragma unroll
  for (int i = 0; i < 3; ++i)
#pragma unroll
    for (int j = 0; j < 3; ++j)
      C[i*3+j] = A[i*3+0]*Bm[0*3+j] + A[i*3+1]*Bm[1*3+j] + A[i*3+2]*Bm[2*3+j];
}

__device__ void se3_exp_dev(const float* x, float* R, float* p) {
  float wx = x[0], wy = x[1], wz = x[2];
  float vx = x[3], vy = x[4], vz = x[5];
  float t2 = wx*wx + wy*wy + wz*wz;
  float t = sqrtf(t2);
  float A, Bc, Cc;
  if (t < 1e-6f) {
    A  = 1.f - t2*(1.f/6.f);
    Bc = 0.5f - t2*(1.f/24.f);
    Cc = (1.f/6.f) - t2*(1.f/120.f);
  } else {
    float s = sinf(t), c = cosf(t);
    A  = s / t;
    Bc = (1.f - c) / t2;
    Cc = (t - s) / (t2 * t);
  }
  float W[9]  = {0.f, -wz, wy,  wz, 0.f, -wx,  -wy, wx, 0.f};
  float W2[9];
  mat3mul(W, W, W2);
#pragma unroll
  for (int i = 0; i < 9; ++i) {
    float I = (i == 0 || i == 4 || i == 8) ? 1.f : 0.f;
    R[i] = I + A*W[i] + Bc*W2[i];
  }
  float V[9];
#pragma unroll
  for (int i = 0; i < 9; ++i) {
    float I = (i == 0 || i == 4 || i == 8) ? 1.f : 0.f;
    V[i] = I + Bc*W[i] + Cc*W2[i];
  }
  p[0] = V[0]*vx + V[1]*vy + V[2]*vz;
  p[1] = V[3]*vx + V[4]*vy + V[5]*vz;
  p[2] = V[6]*vx + V[7]*vy + V[8]*vz;
}

// ---------------- fused prep: pack_w3 (blk 0-127), pack_w2 (128-159),
// means (160-175), setup (176). One dispatch instead of four. ----------------
__global__ void prep_kernel(
    const float* __restrict__ p_src, const float* __restrict__ p_tgt,
    const float* __restrict__ igt_twist, const float* __restrict__ dt,
    const float* __restrict__ W1, const float* __restrict__ b1,
    const float* __restrict__ W2, const float* __restrict__ W3,
    float* __restrict__ mean_tgt, float* __restrict__ mean_src,
    float* __restrict__ W1eff7, float* __restrict__ b1eff7,
    float* __restrict__ W1effL, float* __restrict__ b1effL,
    float* __restrict__ g_buf, float* __restrict__ igt_inv,
    float* __restrict__ loss_out,
    _Float16* __restrict__ W2h, _Float16* __restrict__ W2l,
    _Float16* __restrict__ W3p) {
  const int blk = blockIdx.x, t = threadIdx.x;
  __shared__ float red[256][3];
  if (blk < 128) {
    // pack_w3: W3p[nt][lev][ks3][lane][8], 8 KB per nt tile
#pragma unroll
    for (int u = 0; u < 4; ++u) {
      int i = blk*1024 + u*256 + t;   // 128*1024 total
      int k = i >> 10, n = i & 1023;
      _Float16 hi, lo;
      split_f16s(W3[i], hi, lo);
      int nt = n >> 4, col = n & 15;
      int ks3 = k >> 5, rr = k & 31;
      int lane = (rr >> 3)*16 + col, jj = rr & 7;
      size_t base = (size_t)nt*4096;
      W3p[base + ((0*4 + ks3)*64 + lane)*8 + jj] = hi;
      W3p[base + ((1*4 + ks3)*64 + lane)*8 + jj] = lo;
    }
  } else if (blk < 160) {
    int i = (blk - 128)*256 + t;   // 64*128
    int k = i >> 7, n = i & 127;
    _Float16 hi, lo;
    split_f16s(W2[i], hi, lo);
    int nt2 = n >> 4, col = n & 15;
    int ks = k >> 5, rr = k & 31;
    int lane = (rr >> 3)*16 + col, jj = rr & 7;
    int dst = ((nt2*2 + ks)*64 + lane)*8 + jj;
    W2h[dst] = hi; W2l[dst] = lo;
  } else if (blk < 176) {
    int unit = blk - 160;
    int which = unit & 1, b = unit >> 1;
    const float* p = (which ? p_src : p_tgt) + (size_t)b*NPTS*3;
    float* m = (which ? mean_src : mean_tgt) + b*3;
    float s0 = 0.f, s1 = 0.f, s2 = 0.f;
    for (int i = t; i < NPTS; i += 256) {
      s0 += p[i*3+0]; s1 += p[i*3+1]; s2 += p[i*3+2];
    }
    red[t][0] = s0; red[t][1] = s1; red[t][2] = s2;
    __syncthreads();
    for (int s = 128; s > 0; s >>= 1) {
      if (t < s) { red[t][0] += red[t+s][0]; red[t][1] += red[t+s][1]; red[t][2] += red[t+s][2]; }
      __syncthreads();
    }
    if (t == 0) {
      m[0] = red[0][0] * (1.f/NPTS);
      m[1] = red[0][1] * (1.f/NPTS);
      m[2] = red[0][2] * (1.f/NPTS);
    }
  } else {
    // setup
    for (int i = t; i < BATCH*192;  i += 256) W1effL[i] = W1[i % 192];
    for (int i = t; i < BATCH*64;   i += 256) b1effL[i] = b1[i & 63];
    if (t < 192) W1eff7[t] = W1[t];
    if (t < 64)  b1eff7[t] = b1[t];
    if (t < BATCH*16) {
      int i = t & 15;
      g_buf[t] = (i == 0 || i == 5 || i == 10 || i == 15) ? 1.f : 0.f;
    }
    if (t == 0) *loss_out = 0.f;
    if (t < 6) {
      float tw[6] = {0.f,0.f,0.f,0.f,0.f,0.f};
      tw[t] = -dt[t];
      float R[9], tr[3];
      se3_exp_dev(tw, R, tr);
      float* Wd = W1eff7 + (t+1)*192;
      for (int d = 0; d < 3; ++d)
        for (int c = 0; c < 64; ++c)
          Wd[d*64+c] = R[0*3+d]*W1[c] + R[1*3+d]*W1[64+c] + R[2*3+d]*W1[128+c];
      float* bd = b1eff7 + (t+1)*64;
      for (int c = 0; c < 64; ++c)
        bd[c] = b1[c] + tr[0]*W1[c] + tr[1]*W1[64+c] + tr[2]*W1[128+c];
    }
    if (t >= 32 && t < 32+BATCH) {
      int b = t - 32;
      float R[9], tr[3];
      se3_exp_dev(igt_twist + b*6, R, tr);
      float* inv = igt_inv + b*12;
      for (int r = 0; r < 3; ++r) {
        inv[r*4+0] = R[0*3+r];
        inv[r*4+1] = R[1*3+r];
        inv[r*4+2] = R[2*3+r];
        inv[r*4+3] = -(R[0*3+r]*tr[0] + R[1*3+r]*tr[1] + R[2*3+r]*tr[2]);
      }
    }
  }
}

// ---------------- shared encode pieces ----------------
__device__ __forceinline__ f32x4 zero4() {
  f32x4 z; z[0]=0.f; z[1]=0.f; z[2]=0.f; z[3]=0.f; return z;
}

// layer1 + layer2 (3-product) for one ptile -> layer-3 A fragments, via
// per-wave LDS relayout scratch. b3 dropped everywhere (cancels in J and r).
__device__ __forceinline__ void l12_ptile(
    float px, float py, float pz,
    const float* __restrict__ w1, const float* __restrict__ bb1,
    const _Float16* __restrict__ W2h, const _Float16* __restrict__ W2l,
    const float* __restrict__ b2,
    _Float16* scr, int l, int lm, int q,
    f16x8 (&A3h)[4], f16x8 (&A3l)[4]) {
  f16x8 A2h[2], A2l[2];
#pragma unroll
  for (int ks = 0; ks < 2; ++ks) {
    const int c0 = ks*32 + q*8;
    float wa[8], wb[8], wc[8], bv[8];
    *(float4*)&wa[0] = *(const float4*)(w1 + c0);
    *(float4*)&wa[4] = *(const float4*)(w1 + c0 + 4);
    *(float4*)&wb[0] = *(const float4*)(w1 + 64 + c0);
    *(float4*)&wb[4] = *(const float4*)(w1 + 64 + c0 + 4);
    *(float4*)&wc[0] = *(const float4*)(w1 + 128 + c0);
    *(float4*)&wc[4] = *(const float4*)(w1 + 128 + c0 + 4);
    *(float4*)&bv[0] = *(const float4*)(bb1 + c0);
    *(float4*)&bv[4] = *(const float4*)(bb1 + c0 + 4);
#pragma unroll
    for (int jj = 0; jj < 8; ++jj) {
      float h = fmaf(px, wa[jj], fmaf(py, wb[jj], fmaf(pz, wc[jj], bv[jj])));
      h = fmaxf(h, 0.f);
      _Float16 hi, lo;
      split_f16s(h, hi, lo);
      A2h[ks][jj] = hi; A2l[ks][jj] = lo;
    }
  }
#pragma unroll
  for (int nt2 = 0; nt2 < 8; ++nt2) {
    f32x4 acc = zero4();
#pragma unroll
    for (int ks = 0; ks < 2; ++ks) {
      const int base = ((nt2*2 + ks)*64 + l)*8;
      const f16x8 Bh = *(const f16x8*)(W2h + base);
      const f16x8 Bl = *(const f16x8*)(W2l + base);
      acc = MFMA16(A2l[ks], Bh, acc);
      acc = MFMA16(A2h[ks], Bl, acc);
      acc = MFMA16(A2h[ks], Bh, acc);
    }
    const int c2 = nt2*16 + lm;
    const float b2v = b2[c2];
    const int ks3 = c2 >> 5;
    const int k31 = c2 & 31;
    const int qw = k31 >> 3, jw = k31 & 7;
#pragma unroll
    for (int r = 0; r < 4; ++r) {
      const int mrow = q*4 + r;
      float h = fmaxf(acc[r]*INV16 + b2v, 0.f);
      _Float16 hi, lo;
      split_f16s(h, hi, lo);
      const int idx = (ks3*64 + qw*16 + mrow)*8 + jw;
      scr[idx] = hi;
      scr[2048 + idx] = lo;
    }
  }
#pragma unroll
  for (int ks3 = 0; ks3 < 4; ++ks3) {
    const int base = (ks3*64 + l)*8;
    A3h[ks3] = *(const f16x8*)&scr[base];
    A3l[ks3] = *(const f16x8*)&scr[2048 + base];
  }
}

// ---------------- BIG encode: 4 ptiles/wave, LDS B dbuf, in-block cross-wave
// max -> 8 partial slots (one per pblk). grid (8,7,8) x 256. ----------------
__global__ __launch_bounds__(256, 2) void encode_big(
    const float* __restrict__ pts, const float* __restrict__ mean,
    const float* __restrict__ W1e, const float* __restrict__ b1e,
    const _Float16* __restrict__ W2h, const _Float16* __restrict__ W2l,
    const _Float16* __restrict__ W3p, const float* __restrict__ b2,
    float* __restrict__ partial) {
  const int t = threadIdx.x;
  const int w = t >> 6, l = t & 63;
  const int lm = l & 15, q = l >> 4;
  const int pblk = blockIdx.x;
  const int j = blockIdx.y;
  const int b = blockIdx.z;

  __shared__ __align__(16) _Float16 smem[16384];   // 32 KB

  const int ptbase = pblk*256 + w*64;
  float mx0 = mean[b*3+0], my0 = mean[b*3+1], mz0 = mean[b*3+2];
  const float* w1 = W1e + j*192;
  const float* bb1 = b1e + j*64;

  f16x8 A3h[4][4], A3l[4][4];
  _Float16* scr = smem + w*4096;
#pragma unroll
  for (int p = 0; p < 4; ++p) {
    const float* pp = pts + ((size_t)b*NPTS + ptbase + p*16 + lm)*3;
    l12_ptile(pp[0]-mx0, pp[1]-my0, pp[2]-mz0, w1, bb1, W2h, W2l, b2,
              scr, l, lm, q, A3h[p], A3l[p]);
  }
  __syncthreads();   // scr done; smem: [0,16KB) B dbuf, [16KB,32KB) maxbuf

  float* maxb = (float*)(smem + 8192);   // float[4][1024]
  {
    f16x8 s0 = *(const f16x8*)(W3p + t*8);
    f16x8 s1 = *(const f16x8*)(W3p + 2048 + t*8);
    *(f16x8*)&smem[t*8] = s0;
    *(f16x8*)&smem[2048 + t*8] = s1;
  }
  __syncthreads();

  for (int k = 0; k < 64; ++k) {
    const int cur = (k & 1)*4096;
    const int nxt = cur ^ 4096;
    f16x8 s0, s1;
    const int have_next = (k + 1 < 64);
    if (have_next) {
      const _Float16* src = W3p + (size_t)(k+1)*4096;
      s0 = *(const f16x8*)(src + t*8);
      s1 = *(const f16x8*)(src + 2048 + t*8);
    }
    f16x8 B[2][4];
#pragma unroll
    for (int lev = 0; lev < 2; ++lev)
#pragma unroll
      for (int ks = 0; ks < 4; ++ks)
        B[lev][ks] = *(const f16x8*)&smem[cur + ((lev*4 + ks)*64 + l)*8];

    f32x4 a[4] = {zero4(), zero4(), zero4(), zero4()};
#pragma unroll
    for (int ks = 0; ks < 4; ++ks) {
#pragma unroll
      for (int p = 0; p < 4; ++p) a[p] = MFMA16(A3l[p][ks], B[0][ks], a[p]);  // l*h
#pragma unroll
      for (int p = 0; p < 4; ++p) a[p] = MFMA16(A3h[p][ks], B[1][ks], a[p]);  // h*l
#pragma unroll
      for (int p = 0; p < 4; ++p) a[p] = MFMA16(A3h[p][ks], B[0][ks], a[p]);  // h*h
    }
    float mx = -INFINITY;
#pragma unroll
    for (int p = 0; p < 4; ++p)
#pragma unroll
      for (int r = 0; r < 4; ++r) mx = fmaxf(mx, a[p][r]);
    mx = fmaxf(mx, __shfl_xor(mx, 16, 64));
    mx = fmaxf(mx, __shfl_xor(mx, 32, 64));
    if (l < 16) maxb[w*1024 + k*16 + lm] = mx;

    if (have_next) {
      *(f16x8*)&smem[nxt + t*8] = s0;
      *(f16x8*)&smem[nxt + 2048 + t*8] = s1;
    }
    __syncthreads();
  }
  // cross-wave max -> one partial slot per block
  float* pout = partial + ((size_t)(j*BATCH + b)*8 + pblk)*KF;
  for (int f = t; f < KF; f += 256) {
    float m = fmaxf(fmaxf(maxb[f], maxb[1024+f]), fmaxf(maxb[2048+f], maxb[3072+f]));
    pout[f] = m*INV16;
  }
}

// ---------------- pinv: grid(8) x 512 thr (2 k/thread, 8 waves).
// 6x6 SPD inverse on thread 0 via FULLY HAND-SCALARIZED f64 Cholesky —
// named scalars only, no arrays/loops, so it cannot go to scratch.
// (R9-R11's array-form GE/Cholesky spilled: ~200-500 serial scratch accesses
// = 80-123 us at VALUBusy~0.001%.) ----------------
__global__ __launch_bounds__(512) void pinv_kernel(
    const float* __restrict__ partialB, const float* __restrict__ dt,
    float* __restrict__ pinvb, float* __restrict__ feats0) {
  const int b = blockIdx.x, t = threadIdx.x;
  float Jk2[2][6];
  float H[21];
#pragma unroll
  for (int i = 0; i < 21; ++i) H[i] = 0.f;
#pragma unroll
  for (int h = 0; h < 2; ++h) {
    const int kf = t + h*512;
    float fv[7];
#pragma unroll
    for (int j = 0; j < 7; ++j) {
      const float* ps = partialB + ((size_t)(j*BATCH + b)*8)*KF + kf;
      float m = ps[0];
#pragma unroll
      for (int s = 1; s < 8; ++s) m = fmaxf(m, ps[(size_t)s*KF]);
      fv[j] = m;
    }
    feats0[(size_t)b*KF + kf] = fv[0];
#pragma unroll
    for (int i = 0; i < 6; ++i) Jk2[h][i] = (fv[0] - fv[1+i]) / dt[i];
    int idx = 0;
#pragma unroll
    for (int i = 0; i < 6; ++i)
#pragma unroll
      for (int jj = i; jj < 6; ++jj) H[idx++] += Jk2[h][i]*Jk2[h][jj];
  }
#pragma unroll
  for (int i = 0; i < 21; ++i) {
    float v = H[i];
#pragma unroll
    for (int o = 1; o < 64; o <<= 1) v += __shfl_xor(v, o, 64);
    H[i] = v;
  }
  __shared__ float hred[8*21];
  __shared__ float s_hinv[36];
  const int wv = t >> 6, ln = t & 63;
  if (ln == 0)
#pragma unroll
    for (int i = 0; i < 21; ++i) hred[wv*21 + i] = H[i];
  __syncthreads();
  if (t == 0) {
    float Ht[21];
#pragma unroll
    for (int i = 0; i < 21; ++i) {
      float s = 0.f;
#pragma unroll
      for (int w2 = 0; w2 < 8; ++w2) s += hred[w2*21 + i];
      Ht[i] = s;
    }
    // H packed upper row-major: [00,01,02,03,04,05, 11,12,13,14,15, 22,23,24,25, 33,34,35, 44,45, 55]
    double h00=Ht[0], h01=Ht[1], h02=Ht[2], h03=Ht[3], h04=Ht[4], h05=Ht[5];
    double h11=Ht[6], h12=Ht[7], h13=Ht[8], h14=Ht[9], h15=Ht[10];
    double h22=Ht[11], h23=Ht[12], h24=Ht[13], h25=Ht[14];
    double h33=Ht[15], h34=Ht[16], h35=Ht[17];
    double h44=Ht[18], h45=Ht[19];
    double h55=Ht[20];
    // Cholesky H = L L^T (named scalars only)
    double l00=sqrt(h00), i00=1.0/l00;
    double l10=h01*i00, l20=h02*i00, l30=h03*i00, l40=h04*i00, l50=h05*i00;
    double l11=sqrt(h11-l10*l10), i11=1.0/l11;
    double l21=(h12-l20*l10)*i11;
    double l31=(h13-l30*l10)*i11;
    double l41=(h14-l40*l10)*i11;
    double l51=(h15-l50*l10)*i11;
    double l22=sqrt(h22-l20*l20-l21*l21), i22=1.0/l22;
    double l32=(h23-l30*l20-l31*l21)*i22;
    double l42=(h24-l40*l20-l41*l21)*i22;
    double l52=(h25-l50*l20-l51*l21)*i22;
    double l33=sqrt(h33-l30*l30-l31*l31-l32*l32), i33=1.0/l33;
    double l43=(h34-l40*l30-l41*l31-l42*l32)*i33;
    double l53=(h35-l50*l30-l51*l31-l52*l32)*i33;
    double l44=sqrt(h44-l40*l40-l41*l41-l42*l42-l43*l43), i44=1.0/l44;
    double l54=(h45-l50*l40-l51*l41-l52*l42-l53*l43)*i44;
    double l55=sqrt(h55-l50*l50-l51*l51-l52*l52-l53*l53-l54*l54), i55=1.0/l55;
    // M = L^{-1} (lower): M_ii = 1/L_ii; M_ij = -(1/L_ii) * sum_{k=j..i-1} L_ik M_kj
    double m00=i00, m11=i11, m22=i22, m33=i33, m44=i44, m55=i55;
    double m10=-i11*(l10*m00);
    double m20=-i22*(l20*m00+l21*m10);
    double m21=-i22*(l21*m11);
    double m30=-i33*(l30*m00+l31*m10+l32*m20);
    double m31=-i33*(l31*m11+l32*m21);
    double m32=-i33*(l32*m22);
    double m40=-i44*(l40*m00+l41*m10+l42*m20+l43*m30);
    double m41=-i44*(l41*m11+l42*m21+l43*m31);
    double m42=-i44*(l42*m22+l43*m32);
    double m43=-i44*(l43*m33);
    double m50=-i55*(l50*m00+l51*m10+l52*m20+l53*m30+l54*m40);
    double m51=-i55*(l51*m11+l52*m21+l53*m31+l54*m41);
    double m52=-i55*(l52*m22+l53*m32+l54*m42);
    double m53=-i55*(l53*m33+l54*m43);
    double m54=-i55*(l54*m44);
    // Hinv = M^T M (k >= max(i,j))
    double v00 = m00*m00+m10*m10+m20*m20+m30*m30+m40*m40+m50*m50;
    double v01 = m10*m11+m20*m21+m30*m31+m40*m41+m50*m51;
    double v02 = m20*m22+m30*m32+m40*m42+m50*m52;
    double v03 = m30*m33+m40*m43+m50*m53;
    double v04 = m40*m44+m50*m54;
    double v05 = m50*m55;
    double v11 = m11*m11+m21*m21+m31*m31+m41*m41+m51*m51;
    double v12 = m21*m22+m31*m32+m41*m42+m51*m52;
    double v13 = m31*m33+m41*m43+m51*m53;
    double v14 = m41*m44+m51*m54;
    double v15 = m51*m55;
    double v22 = m22*m22+m32*m32+m42*m42+m52*m52;
    double v23 = m32*m33+m42*m43+m52*m53;
    double v24 = m42*m44+m52*m54;
    double v25 = m52*m55;
    double v33 = m33*m33+m43*m43+m53*m53;
    double v34 = m43*m44+m53*m54;
    double v35 = m53*m55;
    double v44 = m44*m44+m54*m54;
    double v45 = m54*m55;
    double v55 = m55*m55;
    s_hinv[0]=(float)v00;  s_hinv[1]=(float)v01;  s_hinv[2]=(float)v02;
    s_hinv[3]=(float)v03;  s_hinv[4]=(float)v04;  s_hinv[5]=(float)v05;
    s_hinv[6]=(float)v01;  s_hinv[7]=(float)v11;  s_hinv[8]=(float)v12;
    s_hinv[9]=(float)v13;  s_hinv[10]=(float)v14; s_hinv[11]=(float)v15;
    s_hinv[12]=(float)v02; s_hinv[13]=(float)v12; s_hinv[14]=(float)v22;
    s_hinv[15]=(float)v23; s_hinv[16]=(float)v24; s_hinv[17]=(float)v25;
    s_hinv[18]=(float)v03; s_hinv[19]=(float)v13; s_hinv[20]=(float)v23;
    s_hinv[21]=(float)v33; s_hinv[22]=(float)v34; s_hinv[23]=(float)v35;
    s_hinv[24]=(float)v04; s_hinv[25]=(float)v14; s_hinv[26]=(float)v24;
    s_hinv[27]=(float)v34; s_hinv[28]=(float)v44; s_hinv[29]=(float)v45;
    s_hinv[30]=(float)v05; s_hinv[31]=(float)v15; s_hinv[32]=(float)v25;
    s_hinv[33]=(float)v35; s_hinv[34]=(float)v45; s_hinv[35]=(float)v55;
  }
  __syncthreads();
#pragma unroll
  for (int h = 0; h < 2; ++h) {
    const int kf = t + h*512;
#pragma unroll
    for (int i = 0; i < 6; ++i) {
      float s = 0.f;
#pragma unroll
      for (int jj = 0; jj < 6; ++jj) s += s_hinv[i*6+jj] * Jk2[h][jj];
      pinvb[((size_t)b*6 + i)*KF + kf] = s;
    }
  }
}

// ---------------- LOOP encode: fused l1-l3, cross-wave max -> 32 slots ----------------
// grid (32, 4, 8) x 256; block writes its 256-feature stripe of slot pblk.
__global__ __launch_bounds__(256, 3) void encode_loop(
    const float* __restrict__ pts, const float* __restrict__ mean,
    const float* __restrict__ W1e, const float* __restrict__ b1e,
    const _Float16* __restrict__ W2h, const _Float16* __restrict__ W2l,
    const _Float16* __restrict__ W3p, const float* __restrict__ b2,
    float* __restrict__ partial2) {
  const int t = threadIdx.x;
  const int w = t >> 6, l = t & 63;
  const int lm = l & 15, q = l >> 4;
  const int pblk = blockIdx.x;
  const int fg = blockIdx.y;
  const int b = blockIdx.z;
  const int nt0 = fg*16;

  __shared__ __align__(16) _Float16 smem[16384];

  const int pt = pblk*64 + w*16;
  float mx0 = mean[b*3+0], my0 = mean[b*3+1], mz0 = mean[b*3+2];
  const float* w1 = W1e + b*192;
  const float* bb1 = b1e + b*64;

  f16x8 A3h[4], A3l[4];
  {
    const float* pp = pts + ((size_t)b*NPTS + pt + lm)*3;
    l12_ptile(pp[0]-mx0, pp[1]-my0, pp[2]-mz0, w1, bb1, W2h, W2l, b2,
              smem + w*4096, l, lm, q, A3h, A3l);
  }
  __syncthreads();

  float* maxb = (float*)(smem + 8192);   // float[4][256]
  {
    const _Float16* src = W3p + (size_t)nt0*4096;
    f16x8 s0 = *(const f16x8*)(src + t*8);
    f16x8 s1 = *(const f16x8*)(src + 2048 + t*8);
    *(f16x8*)&smem[t*8] = s0;
    *(f16x8*)&smem[2048 + t*8] = s1;
  }
  __syncthreads();

  for (int k = 0; k < 16; ++k) {
    const int cur = (k & 1)*4096;
    const int nxt = cur ^ 4096;
    f16x8 s0, s1;
    const int have_next = (k + 1 < 16);
    if (have_next) {
      const _Float16* src = W3p + (size_t)(nt0 + k + 1)*4096;
      s0 = *(const f16x8*)(src + t*8);
      s1 = *(const f16x8*)(src + 2048 + t*8);
    }
    f16x8 B[2][4];
#pragma unroll
    for (int lev = 0; lev < 2; ++lev)
#pragma unroll
      for (int ks = 0; ks < 4; ++ks)
        B[lev][ks] = *(const f16x8*)&smem[cur + ((lev*4 + ks)*64 + l)*8];

    f32x4 a = zero4();
#pragma unroll
    for (int ks = 0; ks < 4; ++ks) {
      a = MFMA16(A3l[ks], B[0][ks], a);
      a = MFMA16(A3h[ks], B[1][ks], a);
      a = MFMA16(A3h[ks], B[0][ks], a);
    }
    float mx = fmaxf(fmaxf(a[0], a[1]), fmaxf(a[2], a[3]));
    mx = fmaxf(mx, __shfl_xor(mx, 16, 64));
    mx = fmaxf(mx, __shfl_xor(mx, 32, 64));
    if (l < 16) maxb[w*256 + k*16 + lm] = mx;

    if (have_next) {
      *(f16x8*)&smem[nxt + t*8] = s0;
      *(f16x8*)&smem[nxt + 2048 + t*8] = s1;
    }
    __syncthreads();
  }
  if (t < 256) {
    float m = fmaxf(fmaxf(maxb[t], maxb[256+t]), fmaxf(maxb[512+t], maxb[768+t]));
    partial2[((size_t)b*32 + pblk)*KF + fg*256 + t] = m*INV16;
  }
}

// ---------------- update: grid(8) x 1024 thr. 32-slot max -> f1, r, shfl 6-dot,
// thread-0 GN step. Final iteration also computes the loss (fused; saves the
// separate loss dispatch). ----------------
__global__ __launch_bounds__(1024) void update_kernel(
    const float* __restrict__ feats0, const float* __restrict__ partial2,
    const float* __restrict__ pinv, float* __restrict__ g_buf,
    const float* __restrict__ W1, const float* __restrict__ b1,
    float* __restrict__ W1effL, float* __restrict__ b1effL,
    float* __restrict__ r_out,
    const float* __restrict__ mean_tgt, const float* __restrict__ mean_src,
    const float* __restrict__ p_src, const float* __restrict__ igt_inv,
    float* __restrict__ loss_out, int final_it) {
  const int b = blockIdx.x, t = threadIdx.x;
  const float* ps = partial2 + (size_t)b*32*KF + t;
  float m = ps[0];
#pragma unroll
  for (int s = 1; s < 32; ++s) m = fmaxf(m, ps[(size_t)s*KF]);
  float r = m - feats0[(size_t)b*KF + t];
  r_out[(size_t)b*KF + t] = r;
  float acc[6];
#pragma unroll
  for (int i = 0; i < 6; ++i) acc[i] = pinv[((size_t)b*6+i)*KF + t] * r;
#pragma unroll
  for (int i = 0; i < 6; ++i) {
    float v = acc[i];
#pragma unroll
    for (int o = 1; o < 64; o <<= 1) v += __shfl_xor(v, o, 64);
    acc[i] = v;
  }
  __shared__ float wred[16*6];
  const int wv = t >> 6, ln = t & 63;
  if (ln == 0)
#pragma unroll
    for (int i = 0; i < 6; ++i) wred[wv*6 + i] = acc[i];
  __syncthreads();
  __shared__ float s_g[16];
  __shared__ float s_e[12];
  __shared__ float s_v[12];
  if (t == 0) {
    float dx[6];
    for (int i = 0; i < 6; ++i) {
      float s = 0.f;
      for (int w2 = 0; w2 < 16; ++w2) s += wred[w2*6 + i];
      dx[i] = -s;
    }
    float R[9], p[3];
    se3_exp_dev(dx, R, p);
    float* g = g_buf + b*16;
    float gn[16];
    for (int r2 = 0; r2 < 3; ++r2)
      for (int c = 0; c < 4; ++c)
        gn[r2*4+c] = R[r2*3+0]*g[c] + R[r2*3+1]*g[4+c] + R[r2*3+2]*g[8+c] + p[r2]*g[12+c];
    gn[12] = 0.f; gn[13] = 0.f; gn[14] = 0.f; gn[15] = 1.f;
    for (int i = 0; i < 16; ++i) { g[i] = gn[i]; s_g[i] = gn[i]; }
    if (final_it) {
      const float* p0m = mean_tgt + b*3;
      const float* p1m = mean_src + b*3;
      for (int r2 = 0; r2 < 3; ++r2) {
        s_e[r2*4+0] = gn[r2*4+0];
        s_e[r2*4+1] = gn[r2*4+1];
        s_e[r2*4+2] = gn[r2*4+2];
        s_e[r2*4+3] = gn[r2*4+3]
                    - (gn[r2*4+0]*p1m[0] + gn[r2*4+1]*p1m[1] + gn[r2*4+2]*p1m[2])
                    + p0m[r2];
      }
    }
  }
  if (final_it && t >= 64 && t < 76) s_v[t-64] = igt_inv[b*12 + (t-64)];
  __syncthreads();
  if (!final_it) {
    if (t < 192) {
      int d = t >> 6, c = t & 63;
      W1effL[b*192 + t] = s_g[0*4+d]*W1[c] + s_g[1*4+d]*W1[64+c] + s_g[2*4+d]*W1[128+c];
    } else if (t < 256) {
      int i = t - 192;
      b1effL[b*64 + i] = b1[i] + s_g[3]*W1[i] + s_g[7]*W1[64+i] + s_g[11]*W1[128+i];
    }
  } else {
    // fused loss: this block's batch contribution
    float ls = 0.f;
    for (int n = t; n < NPTS; n += 1024) {
      const float* p = p_src + ((size_t)b*NPTS + n)*3;
      float px = p[0], py = p[1], pz = p[2];
#pragma unroll
      for (int r2 = 0; r2 < 3; ++r2) {
        float d1 = s_e[r2*4+0]*px + s_e[r2*4+1]*py + s_e[r2*4+2]*pz + s_e[r2*4+3];
        float d2 = s_v[r2*4+0]*px + s_v[r2*4+1]*py + s_v[r2*4+2]*pz + s_v[r2*4+3];
        ls += fabsf(d1 - d2);
      }
    }
#pragma unroll
    for (int o = 1; o < 64; o <<= 1) ls += __shfl_xor(ls, o, 64);
    __shared__ float lred[16];
    if (ln == 0) lred[wv] = ls;
    __syncthreads();
    if (t == 0) {
      float s = 0.f;
      for (int w2 = 0; w2 < 16; ++w2) s += lred[w2];
      atomicAdd(loss_out, s * (1.f/((float)BATCH*NPTS*3)));
    }
  }
}

// ---------------- launcher ----------------
extern "C" void kernel_launch(void* const* d_in, const int* in_sizes, int n_in,
                              void* d_out, int out_size, void* d_ws, size_t ws_size,
                              hipStream_t stream) {
  const float* p_src     = (const float*)d_in[0];
  const float* p_tgt     = (const float*)d_in[1];
  const float* igt_twist = (const float*)d_in[2];
  const float* dt        = (const float*)d_in[3];
  const float* W1        = (const float*)d_in[4];
  const float* b1        = (const float*)d_in[5];
  const float* W2        = (const float*)d_in[6];
  const float* b2        = (const float*)d_in[7];
  const float* W3        = (const float*)d_in[8];
  float* out = (float*)d_out;

  float* ws = (float*)d_ws;
  float* mean_tgt = ws;  ws += 32;
  float* mean_src = ws;  ws += 32;
  float* W1eff7   = ws;  ws += 7*192;
  float* b1eff7   = ws;  ws += 7*64;
  float* feats0   = ws;  ws += BATCH*KF;
  float* W1effL   = ws;  ws += BATCH*192;
  float* b1effL   = ws;  ws += BATCH*64;
  float* g_buf    = ws;  ws += BATCH*16;
  float* pinvb    = ws;  ws += BATCH*6*KF;
  float* igt_inv  = ws;  ws += 96;
  _Float16* W2h = (_Float16*)ws;  ws += 8192/2;
  _Float16* W2l = (_Float16*)ws;  ws += 8192/2;
  _Float16* W3p = (_Float16*)ws;  ws += 262144/2;   // 64 tiles x 8 KB
  float* partialB = ws;  ws += 56*8*KF;             // big-encode partials (1.75 MB)
  float* partial2 = ws;  ws += BATCH*32*KF;         // loop-encode partials (1 MB)

  float* r_out    = out;
  float* loss_out = out + BATCH*KF;

  prep_kernel<<<dim3(177), 256, 0, stream>>>(
      p_src, p_tgt, igt_twist, dt, W1, b1, W2, W3,
      mean_tgt, mean_src, W1eff7, b1eff7, W1effL, b1effL, g_buf, igt_inv,
      loss_out, W2h, W2l, W3p);

  encode_big<<<dim3(8, 7, BATCH), 256, 0, stream>>>(
      p_tgt, mean_tgt, W1eff7, b1eff7, W2h, W2l, W3p, b2, partialB);
  pinv_kernel<<<dim3(BATCH), 512, 0, stream>>>(partialB, dt, pinvb, feats0);

  for (int it = 0; it < 5; ++it) {
    encode_loop<<<dim3(32, 4, BATCH), 256, 0, stream>>>(
        p_src, mean_src, W1effL, b1effL, W2h, W2l, W3p, b2, partial2);
    update_kernel<<<dim3(BATCH), 1024, 0, stream>>>(
        feats0, partial2, pinvb, g_buf, W1, b1, W1effL, b1effL, r_out,
        mean_tgt, mean_src, p_src, igt_inv, loss_out, (it == 4) ? 1 : 0);
  }
}